// Round 4
// baseline (344.726 us; speedup 1.0000x reference)
//
#include <hip/hip_runtime.h>

typedef unsigned int uint32;

using bf16x8 = __attribute__((ext_vector_type(8))) short;
using f32x4  = __attribute__((ext_vector_type(4))) float;

#define B_  16
#define T_  1024
#define D_  512
#define H_  8
#define HD_ 64
#define FFN_ 2048
#define SEH_ 256
#define EPS_ 1e-5f

#define AS1 __attribute__((address_space(1)))
#define AS3 __attribute__((address_space(3)))

__device__ __forceinline__ ushort f2bf(float f) {
  uint32 x = __float_as_uint(f);
  return (ushort)((x + 0x7fffu + ((x >> 16) & 1u)) >> 16);
}
__device__ __forceinline__ float bf2f(ushort u) {
  return __uint_as_float(((uint32)u) << 16);
}
// tanh-form GELU (max |err| vs exact ~3e-4, far under threshold + bf16 rounding)
__device__ __forceinline__ float gelu_fast(float v) {
  float u = v * (0.7978845608f + 0.0356774081f * v * v);
  float e = __expf(2.0f * u);
  float t = 1.0f - 2.0f * __builtin_amdgcn_rcpf(e + 1.0f);
  return 0.5f * v * (1.0f + t);
}

// ---------------- fused weight prep: fp32 (K,N) -> bf16 (N,K), all 5 weights ----------------
__global__ __launch_bounds__(256) void cast_transpose_all_k(
    const float* __restrict__ wq, const float* __restrict__ wk,
    const float* __restrict__ wv, const float* __restrict__ w1,
    const float* __restrict__ w2, ushort* __restrict__ wqkvT,
    ushort* __restrict__ w1T, ushort* __restrict__ w2T) {
  __shared__ float tile[32][33];
  int bid = blockIdx.x;
  const float* W; ushort* WT; int K, N, bk, bn;
  if (bid < 768) {
    int w = bid >> 8, r = bid & 255;
    W = (w == 0) ? wq : (w == 1) ? wk : wv;
    WT = wqkvT + (size_t)w * 512 * 512;
    K = 512; N = 512; bk = (r >> 4) * 32; bn = (r & 15) * 32;
  } else if (bid < 1792) {
    int r = bid - 768;
    W = w1; WT = w1T; K = 512; N = 2048; bk = (r >> 6) * 32; bn = (r & 63) * 32;
  } else {
    int r = bid - 1792;
    W = w2; WT = w2T; K = 2048; N = 512; bk = (r >> 4) * 32; bn = (r & 15) * 32;
  }
  int lx = threadIdx.x & 31;
  int ly = threadIdx.x >> 5;  // 0..7
  #pragma unroll
  for (int i = ly; i < 32; i += 8)
    tile[i][lx] = W[(size_t)(bk + i) * N + bn + lx];
  __syncthreads();
  #pragma unroll
  for (int i = ly; i < 32; i += 8)
    WT[(size_t)(bn + i) * K + bk + lx] = f2bf(tile[lx][i]);
}

// ---------------- SE: y[b][t] = mean_D x ----------------
__global__ __launch_bounds__(256) void se_rowmean_k(const float* __restrict__ x,
                                                    float* __restrict__ y) {
  int row  = blockIdx.x * 4 + (threadIdx.x >> 6);
  int lane = threadIdx.x & 63;
  const float4* p = (const float4*)(x + (size_t)row * D_);
  float4 a = p[lane * 2];
  float4 b = p[lane * 2 + 1];
  float s = a.x + a.y + a.z + a.w + b.x + b.y + b.z + b.w;
  #pragma unroll
  for (int m = 1; m < 64; m <<= 1) s += __shfl_xor(s, m);
  if (lane == 0) y[row] = s * (1.0f / D_);
}

// ---------------- SE: z = relu(y @ se_w1) ---- grid (B_, 8), split-K ----------------
__global__ __launch_bounds__(256) void se_mlp1_k(const float* __restrict__ y,
                                                 const float* __restrict__ w1,
                                                 float* __restrict__ z) {
  __shared__ float yb[T_];
  __shared__ float part[8][32];
  int b = blockIdx.x, jt = blockIdx.y;
  int tid = threadIdx.x;
  #pragma unroll
  for (int i = 0; i < 4; i++) yb[tid + i * 256] = y[(size_t)b * T_ + tid + i * 256];
  __syncthreads();
  int tj = tid & 31, tk = tid >> 5;           // 8 k-groups x 32 j
  int j = jt * 32 + tj;
  const float* wp = w1 + (size_t)(tk * 128) * SEH_ + j;
  const float* yp = yb + tk * 128;
  float a0 = 0.f, a1 = 0.f, a2 = 0.f, a3 = 0.f;
  #pragma unroll
  for (int t = 0; t < 128; t += 4) {
    a0 += yp[t]     * wp[(t)     * SEH_];
    a1 += yp[t + 1] * wp[(t + 1) * SEH_];
    a2 += yp[t + 2] * wp[(t + 2) * SEH_];
    a3 += yp[t + 3] * wp[(t + 3) * SEH_];
  }
  part[tk][tj] = (a0 + a1) + (a2 + a3);
  __syncthreads();
  if (tid < 32) {
    float s = 0.f;
    #pragma unroll
    for (int k = 0; k < 8; k++) s += part[k][tid];
    z[(size_t)b * SEH_ + jt * 32 + tid] = fmaxf(s, 0.f);
  }
}

// ---------------- SE: gate = sigmoid(z @ se_w2) ---- grid (B_, 8), split-K ----------------
__global__ __launch_bounds__(256) void se_mlp2_k(const float* __restrict__ z,
                                                 const float* __restrict__ w2,
                                                 float* __restrict__ gate) {
  __shared__ float zb[SEH_];
  __shared__ float part[2][128];
  int b = blockIdx.x, bt = blockIdx.y;
  int tid = threadIdx.x;
  zb[tid & 255] = z[(size_t)b * SEH_ + (tid & 255)];
  __syncthreads();
  int tt = tid & 127, tk = tid >> 7;          // 2 k-groups x 128 t
  int t = bt * 128 + tt;
  const float* wp = w2 + (size_t)(tk * 128) * T_ + t;
  const float* zp = zb + tk * 128;
  float a0 = 0.f, a1 = 0.f, a2 = 0.f, a3 = 0.f;
  #pragma unroll
  for (int j = 0; j < 128; j += 4) {
    a0 += zp[j]     * wp[(j)     * T_];
    a1 += zp[j + 1] * wp[(j + 1) * T_];
    a2 += zp[j + 2] * wp[(j + 2) * T_];
    a3 += zp[j + 3] * wp[(j + 3) * T_];
  }
  part[tk][tt] = (a0 + a1) + (a2 + a3);
  __syncthreads();
  if (tid < 128) {
    float s = part[0][tid] + part[1][tid];
    gate[(size_t)b * T_ + bt * 128 + tid] = 1.0f / (1.0f + __expf(-s));
  }
}

// ---------------- x1 = x*(1+gate); n = LN(x1)*g+b -> bf16 ----------------
__global__ __launch_bounds__(256) void gate_ln1_k(
    const float* __restrict__ x, const float* __restrict__ gate,
    const float* __restrict__ g, const float* __restrict__ beta,
    float* __restrict__ x1, ushort* __restrict__ nbuf) {
  int rid  = blockIdx.x * 4 + (threadIdx.x >> 6);
  int lane = threadIdx.x & 63;
  const float4* xr = (const float4*)(x + (size_t)rid * D_);
  float4 a = xr[lane * 2];
  float4 b = xr[lane * 2 + 1];
  float gv = 1.0f + gate[rid];
  a.x *= gv; a.y *= gv; a.z *= gv; a.w *= gv;
  b.x *= gv; b.y *= gv; b.z *= gv; b.w *= gv;
  float4* x1r = (float4*)(x1 + (size_t)rid * D_);
  x1r[lane * 2]     = a;
  x1r[lane * 2 + 1] = b;
  float s  = a.x + a.y + a.z + a.w + b.x + b.y + b.z + b.w;
  float ss = a.x*a.x + a.y*a.y + a.z*a.z + a.w*a.w + b.x*b.x + b.y*b.y + b.z*b.z + b.w*b.w;
  #pragma unroll
  for (int m = 1; m < 64; m <<= 1) { s += __shfl_xor(s, m); ss += __shfl_xor(ss, m); }
  float mu   = s * (1.0f / D_);
  float var  = ss * (1.0f / D_) - mu * mu;
  float rstd = rsqrtf(var + EPS_);
  const float4* gp = (const float4*)g;
  const float4* bp = (const float4*)beta;
  float4 g0 = gp[lane * 2], g1 = gp[lane * 2 + 1];
  float4 b0 = bp[lane * 2], b1 = bp[lane * 2 + 1];
  union { uint4 v; ushort u[8]; } pk;
  pk.u[0] = f2bf((a.x - mu) * rstd * g0.x + b0.x);
  pk.u[1] = f2bf((a.y - mu) * rstd * g0.y + b0.y);
  pk.u[2] = f2bf((a.z - mu) * rstd * g0.z + b0.z);
  pk.u[3] = f2bf((a.w - mu) * rstd * g0.w + b0.w);
  pk.u[4] = f2bf((b.x - mu) * rstd * g1.x + b1.x);
  pk.u[5] = f2bf((b.y - mu) * rstd * g1.y + b1.y);
  pk.u[6] = f2bf((b.z - mu) * rstd * g1.z + b1.z);
  pk.u[7] = f2bf((b.w - mu) * rstd * g1.w + b1.w);
  *(uint4*)(nbuf + (size_t)rid * D_ + lane * 8) = pk.v;
}

// ---------------- n2 = LN(x2)*g+b -> bf16 ----------------
__global__ __launch_bounds__(256) void ln2_k(
    const float* __restrict__ x2, const float* __restrict__ g,
    const float* __restrict__ beta, ushort* __restrict__ nbuf) {
  int rid  = blockIdx.x * 4 + (threadIdx.x >> 6);
  int lane = threadIdx.x & 63;
  const float4* xr = (const float4*)(x2 + (size_t)rid * D_);
  float4 a = xr[lane * 2];
  float4 b = xr[lane * 2 + 1];
  float s  = a.x + a.y + a.z + a.w + b.x + b.y + b.z + b.w;
  float ss = a.x*a.x + a.y*a.y + a.z*a.z + a.w*a.w + b.x*b.x + b.y*b.y + b.z*b.z + b.w*b.w;
  #pragma unroll
  for (int m = 1; m < 64; m <<= 1) { s += __shfl_xor(s, m); ss += __shfl_xor(ss, m); }
  float mu   = s * (1.0f / D_);
  float var  = ss * (1.0f / D_) - mu * mu;
  float rstd = rsqrtf(var + EPS_);
  const float4* gp = (const float4*)g;
  const float4* bp = (const float4*)beta;
  float4 g0 = gp[lane * 2], g1 = gp[lane * 2 + 1];
  float4 b0 = bp[lane * 2], b1 = bp[lane * 2 + 1];
  union { uint4 v; ushort u[8]; } pk;
  pk.u[0] = f2bf((a.x - mu) * rstd * g0.x + b0.x);
  pk.u[1] = f2bf((a.y - mu) * rstd * g0.y + b0.y);
  pk.u[2] = f2bf((a.z - mu) * rstd * g0.z + b0.z);
  pk.u[3] = f2bf((a.w - mu) * rstd * g0.w + b0.w);
  pk.u[4] = f2bf((b.x - mu) * rstd * g1.x + b1.x);
  pk.u[5] = f2bf((b.y - mu) * rstd * g1.y + b1.y);
  pk.u[6] = f2bf((b.z - mu) * rstd * g1.z + b1.z);
  pk.u[7] = f2bf((b.w - mu) * rstd * g1.w + b1.w);
  *(uint4*)(nbuf + (size_t)rid * D_ + lane * 8) = pk.v;
}

// ---------------- 256-wide bf16 NT GEMM: 4-phase K-tile schedule, counted vmcnt ----------------
// (unchanged from round 3 — see comments there)
#define MFMA16 __builtin_amdgcn_mfma_f32_16x16x32_bf16
template <int BN>
__global__ __launch_bounds__(512, 2) void gemm256_k(
    const ushort* __restrict__ A, const ushort* __restrict__ BT,
    int M, int N, int K,
    const float* __restrict__ bias, const float* __restrict__ resid,
    ushort* __restrict__ outB, ushort* __restrict__ outB2,
    ushort* __restrict__ vTout, float* __restrict__ outF, int epi) {
  constexpr int WNS   = BN / 4;    // wave N-span
  constexpr int NT    = BN / 64;   // 16-col frags per wave (4 or 2)
  constexpr int NH    = NT / 2;    // frags per n-half phase (2 or 1)
  constexpr int BROWS = BN / 8;    // B rows staged per wave
  constexpr int BJ    = BN / 64;   // B stage instrs per wave
  __shared__ ushort smem[2 * 256 * 64 + 2 * BN * 64];
  ushort* As = smem;
  ushort* Bs = smem + 2 * 256 * 64;

  int tid  = threadIdx.x;
  int wave = tid >> 6;
  int lane = tid & 63;
  int quad = lane >> 4;
  int l15  = lane & 15;
  int wm   = wave >> 2;   // 0..1
  int wn   = wave & 3;    // 0..3
  int lr   = lane >> 3;   // stage: row within 8-row group
  int lcs  = (lane & 7) ^ lr;  // stage: swizzled source chunk

  int nbk = N / BN;
  int bid = blockIdx.x;
  int xcd = bid & 7;
  int sb  = bid >> 3;
  int n0  = (sb % nbk) * BN;
  int m0  = ((sb / nbk) * 8 + xcd) * 256;

  f32x4 acc[8][NT];
  #pragma unroll
  for (int i = 0; i < 8; i++)
    #pragma unroll
    for (int j = 0; j < NT; j++) acc[i][j] = (f32x4){0.f, 0.f, 0.f, 0.f};

  const ushort* Ag = A  + (size_t)(m0 + wave * 32 + lr) * K + lcs * 8;
  const ushort* Bg = BT + (size_t)(n0 + wave * BROWS + lr) * K + lcs * 8;

  auto STAGE = [&](int t, int buf) {
    int ko = t * 64;
    ushort* da = As + buf * (256 * 64) + wave * (32 * 64);
    #pragma unroll
    for (int j = 0; j < 4; j++)
      __builtin_amdgcn_global_load_lds((const AS1 void*)(Ag + ko + (size_t)(j * 8) * K),
                                       (AS3 void*)(da + j * 512), 16, 0, 0);
    ushort* db = Bs + buf * (BN * 64) + wave * (BROWS * 64);
    #pragma unroll
    for (int j = 0; j < BJ; j++)
      __builtin_amdgcn_global_load_lds((const AS1 void*)(Bg + ko + (size_t)(j * 8) * K),
                                       (AS3 void*)(db + j * 512), 16, 0, 0);
  };

  int ntt = K >> 6;
  STAGE(0, 0);
  STAGE(1, 1);
  if constexpr (BN == 256) asm volatile("s_waitcnt vmcnt(8)" ::: "memory");
  else                     asm volatile("s_waitcnt vmcnt(6)" ::: "memory");
  __builtin_amdgcn_s_barrier();

  const ushort* Arow = As + (wm * 128 + l15) * 64;
  const ushort* Brow = Bs + (wn * WNS + l15) * 64;
  int c0 = ((0 + quad) ^ (l15 & 7)) * 8;  // k-half 0 swizzled chunk (ushort off)
  int c1 = ((4 + quad) ^ (l15 & 7)) * 8;  // k-half 1

  for (int t = 0; t < ntt; ++t) {
    const ushort* Ab = Arow + (t & 1) * (256 * 64);
    const ushort* Bb = Brow + (t & 1) * (BN * 64);
    bf16x8 a[4][2], b[NT][2];

    // ---- phase (mh=0, nh=0): read A-half0 + B-half0
    #pragma unroll
    for (int m4 = 0; m4 < 4; m4++) {
      a[m4][0] = *(const bf16x8*)(Ab + m4 * 1024 + c0);
      a[m4][1] = *(const bf16x8*)(Ab + m4 * 1024 + c1);
    }
    #pragma unroll
    for (int h = 0; h < NH; h++) {
      b[h][0] = *(const bf16x8*)(Bb + h * 1024 + c0);
      b[h][1] = *(const bf16x8*)(Bb + h * 1024 + c1);
    }
    __builtin_amdgcn_s_barrier();
    asm volatile("s_waitcnt lgkmcnt(0)" ::: "memory");
    __builtin_amdgcn_sched_barrier(0);
    __builtin_amdgcn_s_setprio(1);
    #pragma unroll
    for (int m4 = 0; m4 < 4; m4++)
      #pragma unroll
      for (int h = 0; h < NH; h++) {
        acc[m4][h] = MFMA16(a[m4][0], b[h][0], acc[m4][h], 0, 0, 0);
        acc[m4][h] = MFMA16(a[m4][1], b[h][1], acc[m4][h], 0, 0, 0);
      }
    __builtin_amdgcn_s_setprio(0);
    __builtin_amdgcn_s_barrier();

    // ---- phase (0,1): read B-half1
    #pragma unroll
    for (int h = 0; h < NH; h++) {
      b[NH + h][0] = *(const bf16x8*)(Bb + (NH + h) * 1024 + c0);
      b[NH + h][1] = *(const bf16x8*)(Bb + (NH + h) * 1024 + c1);
    }
    __builtin_amdgcn_s_barrier();
    asm volatile("s_waitcnt lgkmcnt(0)" ::: "memory");
    __builtin_amdgcn_sched_barrier(0);
    __builtin_amdgcn_s_setprio(1);
    #pragma unroll
    for (int m4 = 0; m4 < 4; m4++)
      #pragma unroll
      for (int h = 0; h < NH; h++) {
        acc[m4][NH + h] = MFMA16(a[m4][0], b[NH + h][0], acc[m4][NH + h], 0, 0, 0);
        acc[m4][NH + h] = MFMA16(a[m4][1], b[NH + h][1], acc[m4][NH + h], 0, 0, 0);
      }
    __builtin_amdgcn_s_setprio(0);
    __builtin_amdgcn_s_barrier();

    // ---- phase (1,0): read A-half1 (rows 64..127 of wave tile)
    #pragma unroll
    for (int m4 = 0; m4 < 4; m4++) {
      a[m4][0] = *(const bf16x8*)(Ab + (4 + m4) * 1024 + c0);
      a[m4][1] = *(const bf16x8*)(Ab + (4 + m4) * 1024 + c1);
    }
    __builtin_amdgcn_s_barrier();
    asm volatile("s_waitcnt lgkmcnt(0)" ::: "memory");
    __builtin_amdgcn_sched_barrier(0);
    __builtin_amdgcn_s_setprio(1);
    #pragma unroll
    for (int m4 = 0; m4 < 4; m4++)
      #pragma unroll
      for (int h = 0; h < NH; h++) {
        acc[4 + m4][h] = MFMA16(a[m4][0], b[h][0], acc[4 + m4][h], 0, 0, 0);
        acc[4 + m4][h] = MFMA16(a[m4][1], b[h][1], acc[4 + m4][h], 0, 0, 0);
      }
    __builtin_amdgcn_s_setprio(0);
    __builtin_amdgcn_s_barrier();

    // ---- phase (1,1): no new reads (a = half1, b = half1 already live)
    __builtin_amdgcn_s_setprio(1);
    #pragma unroll
    for (int m4 = 0; m4 < 4; m4++)
      #pragma unroll
      for (int h = 0; h < NH; h++) {
        acc[4 + m4][NH + h] = MFMA16(a[m4][0], b[NH + h][0], acc[4 + m4][NH + h], 0, 0, 0);
        acc[4 + m4][NH + h] = MFMA16(a[m4][1], b[NH + h][1], acc[4 + m4][NH + h], 0, 0, 0);
      }
    __builtin_amdgcn_s_setprio(0);

    // ---- tile boundary: publish tile t+1, keep t+2 loads in flight (counted vmcnt)
    if (t + 1 < ntt) {
      if (t + 2 < ntt) {
        STAGE(t + 2, t & 1);
        if constexpr (BN == 256) asm volatile("s_waitcnt vmcnt(8)" ::: "memory");
        else                     asm volatile("s_waitcnt vmcnt(6)" ::: "memory");
      } else {
        asm volatile("s_waitcnt vmcnt(0)" ::: "memory");
      }
      __builtin_amdgcn_s_barrier();
    }
  }

  // ---------------- epilogues ----------------
  int colbase = n0 + wn * WNS;
  if (epi == 2) {
    // f32 stores: 16 lanes x 4B = 64B fully-dirty aligned lines already
    #pragma unroll
    for (int nt = 0; nt < NT; nt++) {
      int n = colbase + nt * 16 + l15;
      float bv = bias[n];
      #pragma unroll
      for (int mt = 0; mt < 8; mt++) {
        int m = m0 + wm * 128 + mt * 16 + quad * 4;
        #pragma unroll
        for (int r = 0; r < 4; r++) {
          size_t idx = (size_t)(m + r) * N + n;
          outF[idx] = acc[mt][nt][r] + bv + resid[idx];
        }
      }
    }
  } else {
    __syncthreads();   // K-loop LDS dead for ALL waves; safe to reuse (block-uniform path)
    if (epi == 3 && n0 >= 1024) {
      // v: per-wave LDS transpose -> full-line coalesced vT writes.
      constexpr int TST = 136;              // t-stride (ushorts), 16B-aligned rows
      ushort* tb = smem + wave * (32 * TST);
      #pragma unroll
      for (int nt = 0; nt < NT; nt++) {
        int dloc = nt * 16 + l15;           // 0..31
        #pragma unroll
        for (int mt = 0; mt < 8; mt++) {
          ushort4 pk;
          pk.x = f2bf(acc[mt][nt][0]);
          pk.y = f2bf(acc[mt][nt][1]);
          pk.z = f2bf(acc[mt][nt][2]);
          pk.w = f2bf(acc[mt][nt][3]);
          *(ushort4*)(tb + dloc * TST + mt * 16 + quad * 4) = pk;
        }
      }
      // each wave reads back only its own region: per-wave lgkm ordering suffices
      int dbase = (n0 - 1024) + wn * WNS;   // 32-col span
      int bb = m0 >> 10;
      int tg = (m0 & 1023) + wm * 128 + l15 * 8;
      #pragma unroll
      for (int j = 0; j < 8; j++) {
        int dloc = j * 4 + quad;            // 0..31
        int d = dbase + dloc;
        int hh = d >> 6, dd = d & 63;
        uint4 vv = *(const uint4*)(tb + dloc * TST + l15 * 8);
        *(uint4*)(vTout + (((size_t)bb * 8 + hh) * 64 + dd) * 1024 + tg) = vv;
      }
    } else {
      // bf16 row-major outputs (epi 1 FFN1-GELU; epi 3 q/k): stage per-wave
      // 32-row x WNS-col chunks in LDS, read back row-major uint4 runs ->
      // every store covers full 64/128-B aligned runs per row.
      constexpr int RS  = WNS + 8;       // padded LDS row stride (ushorts)
      constexpr int LPR = WNS / 8;       // lanes per row (uint4 = 8 ushorts)
      constexpr int RPS = 64 / LPR;      // rows per store instruction
      ushort* tb = smem + wave * (32 * RS);
      ushort* gout; int ldN; float scl;
      if (epi == 1) { gout = outB; ldN = N; scl = 1.0f; }
      else {
        gout = (n0 < 512) ? outB : outB2; ldN = 512;
        // q scaled by 1/8 * log2(e) so attention can use exp2 directly
        scl = (n0 < 512) ? 0.18033688011112042f : 1.0f;
      }
      int ncol = (epi == 1) ? colbase : ((n0 & 511) + wn * WNS);
      float bv[NT];
      #pragma unroll
      for (int nt = 0; nt < NT; nt++)
        bv[nt] = (epi == 1) ? bias[colbase + nt * 16 + l15] : 0.0f;
      int rrow = lane / LPR;
      int seg  = lane % LPR;
      int mrow0 = m0 + wm * 128;
      #pragma unroll
      for (int mtg = 0; mtg < 4; mtg++) {
        #pragma unroll
        for (int mh = 0; mh < 2; mh++) {
          int mt = mtg * 2 + mh;
          #pragma unroll
          for (int nt = 0; nt < NT; nt++) {
            #pragma unroll
            for (int r = 0; r < 4; r++) {
              float v = (epi == 1) ? gelu_fast(acc[mt][nt][r] + bv[nt])
                                   : acc[mt][nt][r] * scl;
              tb[(mh * 16 + quad * 4 + r) * RS + nt * 16 + l15] = f2bf(v);
            }
          }
        }
        #pragma unroll
        for (int it = 0; it < 32 / RPS; it++) {
          int rl = it * RPS + rrow;
          uint4 v = *(const uint4*)(tb + rl * RS + seg * 8);
          *(uint4*)(gout + (size_t)(mrow0 + mtg * 32 + rl) * ldN + ncol + seg * 8) = v;
        }
      }
    }
  }
}

// ---------------- MFMA flash attention, 128 Q-rows/block, no-max softmax ----------------
// XCD-grouped grid: each XCD owns 16 (b,h) pairs x 8 q-tiles -> K/V (256KB/pair)
// fetched into ONE L2 and reused by the 8 q-tile blocks (was 8x replicated).
// LDS: natural stride 64 + chunk-XOR swizzle (chunk' = chunk ^ (row&7)) on both
// ds_write (reg-staged) and ds_read -> uniform banks on all b128 traffic.
// K/V global loads software-pipelined one kt ahead (latency hides under QK+exp+PV).
// Softmax: q pre-scaled by log2e/8 -> p = exp2(s) via v_exp_f32, no per-elem mul.
__global__ __launch_bounds__(256) void attn_k(
    const ushort* __restrict__ q, const ushort* __restrict__ k,
    const ushort* __restrict__ vT, const float* __restrict__ x1,
    float* __restrict__ out) {
  __shared__ ushort Ks[64 * 64];     // [key][d]   swizzled
  __shared__ ushort Vs[64 * 64];     // [d][key]   swizzled
  __shared__ ushort Ps[128 * 64];    // [qrow][key] swizzled
  int bid = blockIdx.x;
  int xcd = bid & 7;
  int j   = bid >> 3;          // 0..127
  int qt  = j & 7;
  int pair = xcd * 16 + (j >> 3);   // 0..127 = b*8+h
  int b = pair >> 3;
  int h = pair & 7;
  int t0 = qt * 128;
  int tid  = threadIdx.x;
  int wave = tid >> 6;
  int lane = tid & 63;
  int quad = lane >> 4;
  int l15  = lane & 15;

  const ushort* qp0 = q + ((size_t)(b * T_ + t0 + wave * 16 + l15)) * D_ + h * HD_;
  const ushort* qp1 = qp0 + (size_t)64 * D_;
  bf16x8 aq0 = *(const bf16x8*)(qp0 + quad * 8);
  bf16x8 aq1 = *(const bf16x8*)(qp0 + 32 + quad * 8);
  bf16x8 aq2 = *(const bf16x8*)(qp1 + quad * 8);
  bf16x8 aq3 = *(const bf16x8*)(qp1 + 32 + quad * 8);

  int srow = tid >> 2;          // 0..63
  int c2   = (tid & 3) * 2;     // staged chunk pair base (8-ushort chunks)
  int scol = c2 * 8;            // 0,16,32,48 (ushort col)
  int sw0  = ((c2)     ^ (srow & 7)) << 3;   // swizzled LDS chunk offsets
  int sw1  = ((c2 + 1) ^ (srow & 7)) << 3;
  int swb  = srow * 64;
  // read-side swizzled chunk offsets (row&7 == l15&7 for all our reads)
  int rsw0 = ((quad)     ^ (l15 & 7)) << 3;
  int rsw1 = ((quad + 4) ^ (l15 & 7)) << 3;

  float l_part[2][4] = {{0.f, 0.f, 0.f, 0.f}, {0.f, 0.f, 0.f, 0.f}};
  f32x4 o0[4], o1[4];
  #pragma unroll
  for (int dt = 0; dt < 4; dt++) {
    o0[dt] = (f32x4){0.f, 0.f, 0.f, 0.f};
    o1[dt] = (f32x4){0.f, 0.f, 0.f, 0.f};
  }

  const ushort* vTb = vT + ((size_t)(b * 8 + h) * 64 + srow) * 1024 + scol;
  size_t kgb = ((size_t)(b * T_ + srow)) * D_ + h * HD_ + scol;

  // prologue: load kt=0 K/V into regs
  uint4 ku0 = *(const uint4*)(k + kgb);
  uint4 ku1 = *(const uint4*)(k + kgb + 8);
  uint4 vv0 = *(const uint4*)(vTb);
  uint4 vv1 = *(const uint4*)(vTb + 8);

  for (int kt = 0; kt < 16; kt++) {
    __syncthreads();  // all waves done reading Ks/Vs of previous tile

    *(uint4*)(Ks + swb + sw0) = ku0;
    *(uint4*)(Ks + swb + sw1) = ku1;
    *(uint4*)(Vs + swb + sw0) = vv0;
    *(uint4*)(Vs + swb + sw1) = vv1;

    __syncthreads();

    // issue next tile's loads now: latency hides under QK + exp + PV
    if (kt + 1 < 16) {
      size_t kg2 = kgb + (size_t)(kt + 1) * 64 * D_;
      const ushort* vp2 = vTb + (kt + 1) * 64;
      ku0 = *(const uint4*)(k + kg2);
      ku1 = *(const uint4*)(k + kg2 + 8);
      vv0 = *(const uint4*)(vp2);
      vv1 = *(const uint4*)(vp2 + 8);
    }

    f32x4 s0[4], s1[4];
    #pragma unroll
    for (int nt = 0; nt < 4; nt++) {
      const ushort* krow = Ks + (nt * 16 + l15) * 64;
      bf16x8 bk0 = *(const bf16x8*)(krow + rsw0);
      bf16x8 bk1 = *(const bf16x8*)(krow + rsw1);
      f32x4 z = (f32x4){0.f, 0.f, 0.f, 0.f};
      s0[nt] = MFMA16(aq0, bk0, z, 0, 0, 0);
      s0[nt] = MFMA16(aq1, bk1, s0[nt], 0, 0, 0);
      s1[nt] = MFMA16(aq2, bk0, z, 0, 0, 0);
      s1[nt] = MFMA16(aq3, bk1, s1[nt], 0, 0, 0);
    }

    #pragma unroll
    for (int nt = 0; nt < 4; nt++) {
      int cps = nt * 2 + (l15 >> 3);      // unswizzled chunk of col
      #pragma unroll
      for (int r = 0; r < 4; r++) {
        int rowl = quad * 4 + r;          // row within wave's 16-row group
        int off = (wave * 16 + rowl) * 64 + ((cps ^ (rowl & 7)) << 3) + (l15 & 7);
        float p0 = __builtin_amdgcn_exp2f(s0[nt][r]);
        float p1 = __builtin_amdgcn_exp2f(s1[nt][r]);
        l_part[0][r] += p0;
        l_part[1][r] += p1;
        Ps[off]            = f2bf(p0);
        Ps[off + 64 * 64]  = f2bf(p1);    // row+64: same &7 -> same swizzle
      }
    }
    // no barrier: each wave reads back only its own 16+16 Ps rows below

    const ushort* prow = Ps + (wave * 16 + l15) * 64;
    bf16x8 ap0 = *(const bf16x8*)(prow + rsw0);
    bf16x8 ap1 = *(const bf16x8*)(prow + rsw1);
    bf16x8 ap2 = *(const bf16x8*)(prow + 4096 + rsw0);
    bf16x8 ap3 = *(const bf16x8*)(prow + 4096 + rsw1);
    #pragma unroll
    for (int dt = 0; dt < 4; dt++) {
      const ushort* vrow = Vs + (dt * 16 + l15) * 64;
      bf16x8 bv0 = *(const bf16x8*)(vrow + rsw0);
      bf16x8 bv1 = *(const bf16x8*)(vrow + rsw1);
      o0[dt] = MFMA16(ap0, bv0, o0[dt], 0, 0, 0);
      o0[dt] = MFMA16(ap1, bv1, o0[dt], 0, 0, 0);
      o1[dt] = MFMA16(ap2, bv0, o1[dt], 0, 0, 0);
      o1[dt] = MFMA16(ap3, bv1, o1[dt], 0, 0, 0);
    }
  }

  #pragma unroll
  for (int s = 0; s < 2; s++) {
    f32x4* oo = s ? o1 : o0;
    #pragma unroll
    for (int r = 0; r < 4; r++) {
      float l = l_part[s][r];
      l += __shfl_xor(l, 1);
      l += __shfl_xor(l, 2);
      l += __shfl_xor(l, 4);
      l += __shfl_xor(l, 8);
      float inv = 1.0f / l;
      int qrow = t0 + s * 64 + wave * 16 + quad * 4 + r;
      size_t base = ((size_t)(b * T_ + qrow)) * D_ + h * HD_;
      #pragma unroll
      for (int dt = 0; dt < 4; dt++) {
        size_t idx = base + dt * 16 + l15;
        out[idx] = x1[idx] + oo[dt][r] * inv;
      }
    }
  }
}

// ---------------- launch ----------------
extern "C" void kernel_launch(void* const* d_in, const int* in_sizes, int n_in,
                              void* d_out, int out_size, void* d_ws, size_t ws_size,
                              hipStream_t stream) {
  (void)in_sizes; (void)n_in; (void)out_size; (void)ws_size;
  const float* x     = (const float*)d_in[0];
  const float* wq    = (const float*)d_in[1];
  const float* wk    = (const float*)d_in[2];
  const float* wv    = (const float*)d_in[3];
  const float* ln1_g = (const float*)d_in[4];
  const float* ln1_b = (const float*)d_in[5];
  const float* se_w1 = (const float*)d_in[6];
  const float* se_w2 = (const float*)d_in[7];
  const float* ffn_g = (const float*)d_in[8];
  const float* ffn_b = (const float*)d_in[9];
  const float* w1    = (const float*)d_in[10];
  const float* b1    = (const float*)d_in[11];
  const float* w2    = (const float*)d_in[12];
  const float* b2    = (const float*)d_in[13];
  float* out = (float*)d_out;
  char* ws = (char*)d_ws;

  // workspace layout (bytes)
  constexpr size_t X1_OFF   = 0;                         // fp32 x1 (32MB)
  constexpr size_t N_OFF    = 33554432;                  // bf16 n / n2 (16MB)
  constexpr size_t Q_OFF    = 50331648;                  // bf16 q (16MB)
  constexpr size_t K_OFF    = 67108864;                  // bf16 k (16MB)
  constexpr size_t V_OFF    = 83886080;                  // bf16 vT (16MB)
  constexpr size_t H_OFF    = 50331648;                  // bf16 h (reuses q/k/vT; 64MB)
  constexpr size_t WQKV_OFF = 117440512;                 // bf16 wqkvT [1536][512]
  constexpr size_t W1T_OFF  = 119013376;                 // bf16 w1T
  constexpr size_t W2T_OFF  = 121110528;                 // bf16 w2T
  constexpr size_t Y_OFF    = 123207680;
  constexpr size_t Z_OFF    = 123273216;
  constexpr size_t GATE_OFF = 123289600;

  float*  x1    = (float*)(ws + X1_OFF);
  ushort* nbuf  = (ushort*)(ws + N_OFF);
  ushort* qb    = (ushort*)(ws + Q_OFF);
  ushort* kb    = (ushort*)(ws + K_OFF);
  ushort* vT    = (ushort*)(ws + V_OFF);
  ushort* hb    = (ushort*)(ws + H_OFF);
  ushort* wqkvT = (ushort*)(ws + WQKV_OFF);
  ushort* w1T   = (ushort*)(ws + W1T_OFF);
  ushort* w2T   = (ushort*)(ws + W2T_OFF);
  float*  yv    = (float*)(ws + Y_OFF);
  float*  zv    = (float*)(ws + Z_OFF);
  float*  gate  = (float*)(ws + GATE_OFF);

  const int M = B_ * T_;  // 16384

  // 1) all weight cast+transposes in one launch
  cast_transpose_all_k<<<2816, 256, 0, stream>>>(wq, wk, wv, w1, w2, wqkvT, w1T, w2T);

  // 2) SE gate (split-K parallel MLPs)
  se_rowmean_k<<<M / 4, 256, 0, stream>>>(x, yv);
  se_mlp1_k<<<dim3(B_, 8), 256, 0, stream>>>(yv, se_w1, zv);
  se_mlp2_k<<<dim3(B_, 8), 256, 0, stream>>>(zv, se_w2, gate);

  // 3) x1 = x*(1+gate); n = LN1(x1) -> bf16
  gate_ln1_k<<<M / 4, 256, 0, stream>>>(x, gate, ln1_g, ln1_b, x1, nbuf);

  // 4) fused QKV GEMM (q scaled log2e/8, v transposed) — BN=128: 768 blocks
  gemm256_k<128><<<(M / 256) * (1536 / 128), 512, 0, stream>>>(
      nbuf, wqkvT, M, 1536, D_, nullptr, nullptr, qb, kb, vT, nullptr, 3);

  // 5) attention: out(d_out) = x1 + attn (128 Q-rows per block)
  attn_k<<<B_ * H_ * (T_ / 128), 256, 0, stream>>>(qb, kb, vT, x1, out);

  // 6) LN2 -> bf16
  ln2_k<<<M / 4, 256, 0, stream>>>(out, ffn_g, ffn_b, nbuf);

  // 7) FFN — FFN1 256x256 (512 blocks = 2 rounds), FFN2 256x128 (256 = 1 round)
  gemm256_k<256><<<(M / 256) * (FFN_ / 256), 512, 0, stream>>>(
      nbuf, w1T, M, FFN_, D_, b1, nullptr, hb, nullptr, nullptr, nullptr, 1);
  gemm256_k<128><<<(M / 256) * (D_ / 128), 512, 0, stream>>>(
      hb, w2T, M, D_, FFN_, b2, out, nullptr, nullptr, nullptr, out, 2);
}

// Round 5
// 331.734 us; speedup vs baseline: 1.0392x; 1.0392x over previous
//
#include <hip/hip_runtime.h>

typedef unsigned int uint32;

using bf16x8 = __attribute__((ext_vector_type(8))) short;
using f32x4  = __attribute__((ext_vector_type(4))) float;

#define B_  16
#define T_  1024
#define D_  512
#define H_  8
#define HD_ 64
#define FFN_ 2048
#define SEH_ 256
#define EPS_ 1e-5f

#define AS1 __attribute__((address_space(1)))
#define AS3 __attribute__((address_space(3)))

__device__ __forceinline__ ushort f2bf(float f) {
  uint32 x = __float_as_uint(f);
  return (ushort)((x + 0x7fffu + ((x >> 16) & 1u)) >> 16);
}
__device__ __forceinline__ float bf2f(ushort u) {
  return __uint_as_float(((uint32)u) << 16);
}
// packed bf16 pair: lo = bf16(a), hi = bf16(b)  (RTNE, one VALU op)
__device__ __forceinline__ uint32 cvtpk(float a, float b) {
  uint32 r;
  asm("v_cvt_pk_bf16_f32 %0, %1, %2" : "=v"(r) : "v"(a), "v"(b));
  return r;
}
// tanh-form GELU (max |err| vs exact ~3e-4, far under threshold + bf16 rounding)
__device__ __forceinline__ float gelu_fast(float v) {
  float u = v * (0.7978845608f + 0.0356774081f * v * v);
  float e = __expf(2.0f * u);
  float t = 1.0f - 2.0f * __builtin_amdgcn_rcpf(e + 1.0f);
  return 0.5f * v * (1.0f + t);
}

// ---------------- fused weight prep: fp32 (K,N) -> bf16 (N,K), all 5 weights ----------------
__global__ __launch_bounds__(256) void cast_transpose_all_k(
    const float* __restrict__ wq, const float* __restrict__ wk,
    const float* __restrict__ wv, const float* __restrict__ w1,
    const float* __restrict__ w2, ushort* __restrict__ wqkvT,
    ushort* __restrict__ w1T, ushort* __restrict__ w2T) {
  __shared__ float tile[32][33];
  int bid = blockIdx.x;
  const float* W; ushort* WT; int K, N, bk, bn;
  if (bid < 768) {
    int w = bid >> 8, r = bid & 255;
    W = (w == 0) ? wq : (w == 1) ? wk : wv;
    WT = wqkvT + (size_t)w * 512 * 512;
    K = 512; N = 512; bk = (r >> 4) * 32; bn = (r & 15) * 32;
  } else if (bid < 1792) {
    int r = bid - 768;
    W = w1; WT = w1T; K = 512; N = 2048; bk = (r >> 6) * 32; bn = (r & 63) * 32;
  } else {
    int r = bid - 1792;
    W = w2; WT = w2T; K = 2048; N = 512; bk = (r >> 4) * 32; bn = (r & 15) * 32;
  }
  int lx = threadIdx.x & 31;
  int ly = threadIdx.x >> 5;  // 0..7
  #pragma unroll
  for (int i = ly; i < 32; i += 8)
    tile[i][lx] = W[(size_t)(bk + i) * N + bn + lx];
  __syncthreads();
  #pragma unroll
  for (int i = ly; i < 32; i += 8)
    WT[(size_t)(bn + i) * K + bk + lx] = f2bf(tile[lx][i]);
}

// ---------------- SE: y[b][t] = mean_D x ----------------
__global__ __launch_bounds__(256) void se_rowmean_k(const float* __restrict__ x,
                                                    float* __restrict__ y) {
  int row  = blockIdx.x * 4 + (threadIdx.x >> 6);
  int lane = threadIdx.x & 63;
  const float4* p = (const float4*)(x + (size_t)row * D_);
  float4 a = p[lane * 2];
  float4 b = p[lane * 2 + 1];
  float s = a.x + a.y + a.z + a.w + b.x + b.y + b.z + b.w;
  #pragma unroll
  for (int m = 1; m < 64; m <<= 1) s += __shfl_xor(s, m);
  if (lane == 0) y[row] = s * (1.0f / D_);
}

// ---------------- SE: z = relu(y @ se_w1) ---- grid (B_, 8), split-K ----------------
__global__ __launch_bounds__(256) void se_mlp1_k(const float* __restrict__ y,
                                                 const float* __restrict__ w1,
                                                 float* __restrict__ z) {
  __shared__ float yb[T_];
  __shared__ float part[8][32];
  int b = blockIdx.x, jt = blockIdx.y;
  int tid = threadIdx.x;
  #pragma unroll
  for (int i = 0; i < 4; i++) yb[tid + i * 256] = y[(size_t)b * T_ + tid + i * 256];
  __syncthreads();
  int tj = tid & 31, tk = tid >> 5;           // 8 k-groups x 32 j
  int j = jt * 32 + tj;
  const float* wp = w1 + (size_t)(tk * 128) * SEH_ + j;
  const float* yp = yb + tk * 128;
  float a0 = 0.f, a1 = 0.f, a2 = 0.f, a3 = 0.f;
  #pragma unroll
  for (int t = 0; t < 128; t += 4) {
    a0 += yp[t]     * wp[(t)     * SEH_];
    a1 += yp[t + 1] * wp[(t + 1) * SEH_];
    a2 += yp[t + 2] * wp[(t + 2) * SEH_];
    a3 += yp[t + 3] * wp[(t + 3) * SEH_];
  }
  part[tk][tj] = (a0 + a1) + (a2 + a3);
  __syncthreads();
  if (tid < 32) {
    float s = 0.f;
    #pragma unroll
    for (int k = 0; k < 8; k++) s += part[k][tid];
    z[(size_t)b * SEH_ + jt * 32 + tid] = fmaxf(s, 0.f);
  }
}

// ---------------- SE: gate = sigmoid(z @ se_w2) ---- grid (B_, 8), split-K ----------------
__global__ __launch_bounds__(256) void se_mlp2_k(const float* __restrict__ z,
                                                 const float* __restrict__ w2,
                                                 float* __restrict__ gate) {
  __shared__ float zb[SEH_];
  __shared__ float part[2][128];
  int b = blockIdx.x, bt = blockIdx.y;
  int tid = threadIdx.x;
  zb[tid & 255] = z[(size_t)b * SEH_ + (tid & 255)];
  __syncthreads();
  int tt = tid & 127, tk = tid >> 7;          // 2 k-groups x 128 t
  int t = bt * 128 + tt;
  const float* wp = w2 + (size_t)(tk * 128) * T_ + t;
  const float* zp = zb + tk * 128;
  float a0 = 0.f, a1 = 0.f, a2 = 0.f, a3 = 0.f;
  #pragma unroll
  for (int j = 0; j < 128; j += 4) {
    a0 += zp[j]     * wp[(j)     * T_];
    a1 += zp[j + 1] * wp[(j + 1) * T_];
    a2 += zp[j + 2] * wp[(j + 2) * T_];
    a3 += zp[j + 3] * wp[(j + 3) * T_];
  }
  part[tk][tt] = (a0 + a1) + (a2 + a3);
  __syncthreads();
  if (tid < 128) {
    float s = part[0][tid] + part[1][tid];
    gate[(size_t)b * T_ + bt * 128 + tid] = 1.0f / (1.0f + __expf(-s));
  }
}

// ---------------- x1 = x*(1+gate); n = LN(x1)*g+b -> bf16 ----------------
__global__ __launch_bounds__(256) void gate_ln1_k(
    const float* __restrict__ x, const float* __restrict__ gate,
    const float* __restrict__ g, const float* __restrict__ beta,
    float* __restrict__ x1, ushort* __restrict__ nbuf) {
  int rid  = blockIdx.x * 4 + (threadIdx.x >> 6);
  int lane = threadIdx.x & 63;
  const float4* xr = (const float4*)(x + (size_t)rid * D_);
  float4 a = xr[lane * 2];
  float4 b = xr[lane * 2 + 1];
  float gv = 1.0f + gate[rid];
  a.x *= gv; a.y *= gv; a.z *= gv; a.w *= gv;
  b.x *= gv; b.y *= gv; b.z *= gv; b.w *= gv;
  float4* x1r = (float4*)(x1 + (size_t)rid * D_);
  x1r[lane * 2]     = a;
  x1r[lane * 2 + 1] = b;
  float s  = a.x + a.y + a.z + a.w + b.x + b.y + b.z + b.w;
  float ss = a.x*a.x + a.y*a.y + a.z*a.z + a.w*a.w + b.x*b.x + b.y*b.y + b.z*b.z + b.w*b.w;
  #pragma unroll
  for (int m = 1; m < 64; m <<= 1) { s += __shfl_xor(s, m); ss += __shfl_xor(ss, m); }
  float mu   = s * (1.0f / D_);
  float var  = ss * (1.0f / D_) - mu * mu;
  float rstd = rsqrtf(var + EPS_);
  const float4* gp = (const float4*)g;
  const float4* bp = (const float4*)beta;
  float4 g0 = gp[lane * 2], g1 = gp[lane * 2 + 1];
  float4 b0 = bp[lane * 2], b1 = bp[lane * 2 + 1];
  union { uint4 v; ushort u[8]; } pk;
  pk.u[0] = f2bf((a.x - mu) * rstd * g0.x + b0.x);
  pk.u[1] = f2bf((a.y - mu) * rstd * g0.y + b0.y);
  pk.u[2] = f2bf((a.z - mu) * rstd * g0.z + b0.z);
  pk.u[3] = f2bf((a.w - mu) * rstd * g0.w + b0.w);
  pk.u[4] = f2bf((b.x - mu) * rstd * g1.x + b1.x);
  pk.u[5] = f2bf((b.y - mu) * rstd * g1.y + b1.y);
  pk.u[6] = f2bf((b.z - mu) * rstd * g1.z + b1.z);
  pk.u[7] = f2bf((b.w - mu) * rstd * g1.w + b1.w);
  *(uint4*)(nbuf + (size_t)rid * D_ + lane * 8) = pk.v;
}

// ---------------- n2 = LN(x2)*g+b -> bf16 ----------------
__global__ __launch_bounds__(256) void ln2_k(
    const float* __restrict__ x2, const float* __restrict__ g,
    const float* __restrict__ beta, ushort* __restrict__ nbuf) {
  int rid  = blockIdx.x * 4 + (threadIdx.x >> 6);
  int lane = threadIdx.x & 63;
  const float4* xr = (const float4*)(x2 + (size_t)rid * D_);
  float4 a = xr[lane * 2];
  float4 b = xr[lane * 2 + 1];
  float s  = a.x + a.y + a.z + a.w + b.x + b.y + b.z + b.w;
  float ss = a.x*a.x + a.y*a.y + a.z*a.z + a.w*a.w + b.x*b.x + b.y*b.y + b.z*b.z + b.w*b.w;
  #pragma unroll
  for (int m = 1; m < 64; m <<= 1) { s += __shfl_xor(s, m); ss += __shfl_xor(ss, m); }
  float mu   = s * (1.0f / D_);
  float var  = ss * (1.0f / D_) - mu * mu;
  float rstd = rsqrtf(var + EPS_);
  const float4* gp = (const float4*)g;
  const float4* bp = (const float4*)beta;
  float4 g0 = gp[lane * 2], g1 = gp[lane * 2 + 1];
  float4 b0 = bp[lane * 2], b1 = bp[lane * 2 + 1];
  union { uint4 v; ushort u[8]; } pk;
  pk.u[0] = f2bf((a.x - mu) * rstd * g0.x + b0.x);
  pk.u[1] = f2bf((a.y - mu) * rstd * g0.y + b0.y);
  pk.u[2] = f2bf((a.z - mu) * rstd * g0.z + b0.z);
  pk.u[3] = f2bf((a.w - mu) * rstd * g0.w + b0.w);
  pk.u[4] = f2bf((b.x - mu) * rstd * g1.x + b1.x);
  pk.u[5] = f2bf((b.y - mu) * rstd * g1.y + b1.y);
  pk.u[6] = f2bf((b.z - mu) * rstd * g1.z + b1.z);
  pk.u[7] = f2bf((b.w - mu) * rstd * g1.w + b1.w);
  *(uint4*)(nbuf + (size_t)rid * D_ + lane * 8) = pk.v;
}

// ---------------- 256-wide bf16 NT GEMM: 4-phase K-tile schedule, counted vmcnt ----------------
// (unchanged — see round-3 comments)
#define MFMA16 __builtin_amdgcn_mfma_f32_16x16x32_bf16
template <int BN>
__global__ __launch_bounds__(512, 2) void gemm256_k(
    const ushort* __restrict__ A, const ushort* __restrict__ BT,
    int M, int N, int K,
    const float* __restrict__ bias, const float* __restrict__ resid,
    ushort* __restrict__ outB, ushort* __restrict__ outB2,
    ushort* __restrict__ vTout, float* __restrict__ outF, int epi) {
  constexpr int WNS   = BN / 4;    // wave N-span
  constexpr int NT    = BN / 64;   // 16-col frags per wave (4 or 2)
  constexpr int NH    = NT / 2;    // frags per n-half phase (2 or 1)
  constexpr int BROWS = BN / 8;    // B rows staged per wave
  constexpr int BJ    = BN / 64;   // B stage instrs per wave
  __shared__ ushort smem[2 * 256 * 64 + 2 * BN * 64];
  ushort* As = smem;
  ushort* Bs = smem + 2 * 256 * 64;

  int tid  = threadIdx.x;
  int wave = tid >> 6;
  int lane = tid & 63;
  int quad = lane >> 4;
  int l15  = lane & 15;
  int wm   = wave >> 2;   // 0..1
  int wn   = wave & 3;    // 0..3
  int lr   = lane >> 3;   // stage: row within 8-row group
  int lcs  = (lane & 7) ^ lr;  // stage: swizzled source chunk

  int nbk = N / BN;
  int bid = blockIdx.x;
  int xcd = bid & 7;
  int sb  = bid >> 3;
  int n0  = (sb % nbk) * BN;
  int m0  = ((sb / nbk) * 8 + xcd) * 256;

  f32x4 acc[8][NT];
  #pragma unroll
  for (int i = 0; i < 8; i++)
    #pragma unroll
    for (int j = 0; j < NT; j++) acc[i][j] = (f32x4){0.f, 0.f, 0.f, 0.f};

  const ushort* Ag = A  + (size_t)(m0 + wave * 32 + lr) * K + lcs * 8;
  const ushort* Bg = BT + (size_t)(n0 + wave * BROWS + lr) * K + lcs * 8;

  auto STAGE = [&](int t, int buf) {
    int ko = t * 64;
    ushort* da = As + buf * (256 * 64) + wave * (32 * 64);
    #pragma unroll
    for (int j = 0; j < 4; j++)
      __builtin_amdgcn_global_load_lds((const AS1 void*)(Ag + ko + (size_t)(j * 8) * K),
                                       (AS3 void*)(da + j * 512), 16, 0, 0);
    ushort* db = Bs + buf * (BN * 64) + wave * (BROWS * 64);
    #pragma unroll
    for (int j = 0; j < BJ; j++)
      __builtin_amdgcn_global_load_lds((const AS1 void*)(Bg + ko + (size_t)(j * 8) * K),
                                       (AS3 void*)(db + j * 512), 16, 0, 0);
  };

  int ntt = K >> 6;
  STAGE(0, 0);
  STAGE(1, 1);
  if constexpr (BN == 256) asm volatile("s_waitcnt vmcnt(8)" ::: "memory");
  else                     asm volatile("s_waitcnt vmcnt(6)" ::: "memory");
  __builtin_amdgcn_s_barrier();

  const ushort* Arow = As + (wm * 128 + l15) * 64;
  const ushort* Brow = Bs + (wn * WNS + l15) * 64;
  int c0 = ((0 + quad) ^ (l15 & 7)) * 8;  // k-half 0 swizzled chunk (ushort off)
  int c1 = ((4 + quad) ^ (l15 & 7)) * 8;  // k-half 1

  for (int t = 0; t < ntt; ++t) {
    const ushort* Ab = Arow + (t & 1) * (256 * 64);
    const ushort* Bb = Brow + (t & 1) * (BN * 64);
    bf16x8 a[4][2], b[NT][2];

    // ---- phase (mh=0, nh=0): read A-half0 + B-half0
    #pragma unroll
    for (int m4 = 0; m4 < 4; m4++) {
      a[m4][0] = *(const bf16x8*)(Ab + m4 * 1024 + c0);
      a[m4][1] = *(const bf16x8*)(Ab + m4 * 1024 + c1);
    }
    #pragma unroll
    for (int h = 0; h < NH; h++) {
      b[h][0] = *(const bf16x8*)(Bb + h * 1024 + c0);
      b[h][1] = *(const bf16x8*)(Bb + h * 1024 + c1);
    }
    __builtin_amdgcn_s_barrier();
    asm volatile("s_waitcnt lgkmcnt(0)" ::: "memory");
    __builtin_amdgcn_sched_barrier(0);
    __builtin_amdgcn_s_setprio(1);
    #pragma unroll
    for (int m4 = 0; m4 < 4; m4++)
      #pragma unroll
      for (int h = 0; h < NH; h++) {
        acc[m4][h] = MFMA16(a[m4][0], b[h][0], acc[m4][h], 0, 0, 0);
        acc[m4][h] = MFMA16(a[m4][1], b[h][1], acc[m4][h], 0, 0, 0);
      }
    __builtin_amdgcn_s_setprio(0);
    __builtin_amdgcn_s_barrier();

    // ---- phase (0,1): read B-half1
    #pragma unroll
    for (int h = 0; h < NH; h++) {
      b[NH + h][0] = *(const bf16x8*)(Bb + (NH + h) * 1024 + c0);
      b[NH + h][1] = *(const bf16x8*)(Bb + (NH + h) * 1024 + c1);
    }
    __builtin_amdgcn_s_barrier();
    asm volatile("s_waitcnt lgkmcnt(0)" ::: "memory");
    __builtin_amdgcn_sched_barrier(0);
    __builtin_amdgcn_s_setprio(1);
    #pragma unroll
    for (int m4 = 0; m4 < 4; m4++)
      #pragma unroll
      for (int h = 0; h < NH; h++) {
        acc[m4][NH + h] = MFMA16(a[m4][0], b[NH + h][0], acc[m4][NH + h], 0, 0, 0);
        acc[m4][NH + h] = MFMA16(a[m4][1], b[NH + h][1], acc[m4][NH + h], 0, 0, 0);
      }
    __builtin_amdgcn_s_setprio(0);
    __builtin_amdgcn_s_barrier();

    // ---- phase (1,0): read A-half1 (rows 64..127 of wave tile)
    #pragma unroll
    for (int m4 = 0; m4 < 4; m4++) {
      a[m4][0] = *(const bf16x8*)(Ab + (4 + m4) * 1024 + c0);
      a[m4][1] = *(const bf16x8*)(Ab + (4 + m4) * 1024 + c1);
    }
    __builtin_amdgcn_s_barrier();
    asm volatile("s_waitcnt lgkmcnt(0)" ::: "memory");
    __builtin_amdgcn_sched_barrier(0);
    __builtin_amdgcn_s_setprio(1);
    #pragma unroll
    for (int m4 = 0; m4 < 4; m4++)
      #pragma unroll
      for (int h = 0; h < NH; h++) {
        acc[4 + m4][h] = MFMA16(a[m4][0], b[h][0], acc[4 + m4][h], 0, 0, 0);
        acc[4 + m4][h] = MFMA16(a[m4][1], b[h][1], acc[4 + m4][h], 0, 0, 0);
      }
    __builtin_amdgcn_s_setprio(0);
    __builtin_amdgcn_s_barrier();

    // ---- phase (1,1): no new reads (a = half1, b = half1 already live)
    __builtin_amdgcn_s_setprio(1);
    #pragma unroll
    for (int m4 = 0; m4 < 4; m4++)
      #pragma unroll
      for (int h = 0; h < NH; h++) {
        acc[4 + m4][NH + h] = MFMA16(a[m4][0], b[NH + h][0], acc[4 + m4][NH + h], 0, 0, 0);
        acc[4 + m4][NH + h] = MFMA16(a[m4][1], b[NH + h][1], acc[4 + m4][NH + h], 0, 0, 0);
      }
    __builtin_amdgcn_s_setprio(0);

    // ---- tile boundary: publish tile t+1, keep t+2 loads in flight (counted vmcnt)
    if (t + 1 < ntt) {
      if (t + 2 < ntt) {
        STAGE(t + 2, t & 1);
        if constexpr (BN == 256) asm volatile("s_waitcnt vmcnt(8)" ::: "memory");
        else                     asm volatile("s_waitcnt vmcnt(6)" ::: "memory");
      } else {
        asm volatile("s_waitcnt vmcnt(0)" ::: "memory");
      }
      __builtin_amdgcn_s_barrier();
    }
  }

  // ---------------- epilogues ----------------
  int colbase = n0 + wn * WNS;
  if (epi == 2) {
    // f32 stores: 16 lanes x 4B = 64B fully-dirty aligned lines already
    #pragma unroll
    for (int nt = 0; nt < NT; nt++) {
      int n = colbase + nt * 16 + l15;
      float bv = bias[n];
      #pragma unroll
      for (int mt = 0; mt < 8; mt++) {
        int m = m0 + wm * 128 + mt * 16 + quad * 4;
        #pragma unroll
        for (int r = 0; r < 4; r++) {
          size_t idx = (size_t)(m + r) * N + n;
          outF[idx] = acc[mt][nt][r] + bv + resid[idx];
        }
      }
    }
  } else {
    __syncthreads();   // K-loop LDS dead for ALL waves; safe to reuse (block-uniform path)
    if (epi == 3 && n0 >= 1024) {
      // v: per-wave LDS transpose -> full-line coalesced vT writes.
      constexpr int TST = 136;              // t-stride (ushorts), 16B-aligned rows
      ushort* tb = smem + wave * (32 * TST);
      #pragma unroll
      for (int nt = 0; nt < NT; nt++) {
        int dloc = nt * 16 + l15;           // 0..31
        #pragma unroll
        for (int mt = 0; mt < 8; mt++) {
          ushort4 pk;
          pk.x = f2bf(acc[mt][nt][0]);
          pk.y = f2bf(acc[mt][nt][1]);
          pk.z = f2bf(acc[mt][nt][2]);
          pk.w = f2bf(acc[mt][nt][3]);
          *(ushort4*)(tb + dloc * TST + mt * 16 + quad * 4) = pk;
        }
      }
      // each wave reads back only its own region: per-wave lgkm ordering suffices
      int dbase = (n0 - 1024) + wn * WNS;   // 32-col span
      int bb = m0 >> 10;
      int tg = (m0 & 1023) + wm * 128 + l15 * 8;
      #pragma unroll
      for (int j = 0; j < 8; j++) {
        int dloc = j * 4 + quad;            // 0..31
        int d = dbase + dloc;
        int hh = d >> 6, dd = d & 63;
        uint4 vv = *(const uint4*)(tb + dloc * TST + l15 * 8);
        *(uint4*)(vTout + (((size_t)bb * 8 + hh) * 64 + dd) * 1024 + tg) = vv;
      }
    } else {
      // bf16 row-major outputs (epi 1 FFN1-GELU; epi 3 q/k): stage per-wave
      // 32-row x WNS-col chunks in LDS, read back row-major uint4 runs ->
      // every store covers full 64/128-B aligned runs per row.
      constexpr int RS  = WNS + 8;       // padded LDS row stride (ushorts)
      constexpr int LPR = WNS / 8;       // lanes per row (uint4 = 8 ushorts)
      constexpr int RPS = 64 / LPR;      // rows per store instruction
      ushort* tb = smem + wave * (32 * RS);
      ushort* gout; int ldN; float scl;
      if (epi == 1) { gout = outB; ldN = N; scl = 1.0f; }
      else {
        gout = (n0 < 512) ? outB : outB2; ldN = 512;
        // q scaled by 1/8 * log2(e) so attention can use exp2 directly
        scl = (n0 < 512) ? 0.18033688011112042f : 1.0f;
      }
      int ncol = (epi == 1) ? colbase : ((n0 & 511) + wn * WNS);
      float bv[NT];
      #pragma unroll
      for (int nt = 0; nt < NT; nt++)
        bv[nt] = (epi == 1) ? bias[colbase + nt * 16 + l15] : 0.0f;
      int rrow = lane / LPR;
      int seg  = lane % LPR;
      int mrow0 = m0 + wm * 128;
      #pragma unroll
      for (int mtg = 0; mtg < 4; mtg++) {
        #pragma unroll
        for (int mh = 0; mh < 2; mh++) {
          int mt = mtg * 2 + mh;
          #pragma unroll
          for (int nt = 0; nt < NT; nt++) {
            #pragma unroll
            for (int r = 0; r < 4; r++) {
              float v = (epi == 1) ? gelu_fast(acc[mt][nt][r] + bv[nt])
                                   : acc[mt][nt][r] * scl;
              tb[(mh * 16 + quad * 4 + r) * RS + nt * 16 + l15] = f2bf(v);
            }
          }
        }
        #pragma unroll
        for (int it = 0; it < 32 / RPS; it++) {
          int rl = it * RPS + rrow;
          uint4 v = *(const uint4*)(tb + rl * RS + seg * 8);
          *(uint4*)(gout + (size_t)(mrow0 + mtg * 32 + rl) * ldN + ncol + seg * 8) = v;
        }
      }
    }
  }
}

// ---------------- MFMA flash attention, 256 Q-rows/block, 8 waves, no-max softmax ----------------
// 512 blocks = exactly 2 co-resident blocks/CU (LDS 64KB each) = 16 waves/CU.
// XCD-grouped grid: each XCD owns 16 (b,h) pairs x 4 q-tiles -> K/V L2-resident.
// K/V staged via global_load_lds (1 K + 1 V DMA instr per wave per kt, no reg
// round-trip, no prefetch VGPRs), double-buffered -> ONE __syncthreads per kt.
// Swizzle: LDS dest linear, per-lane GLOBAL source chunk pre-swizzled
// ((l&7)^(l>>3)); reads use chunk^(row&7). P packing via v_cvt_pk_bf16_f32.
// Softmax: q pre-scaled by log2e/8 -> p = exp2(s).
__global__ __launch_bounds__(512, 2) void attn_k(
    const ushort* __restrict__ q, const ushort* __restrict__ k,
    const ushort* __restrict__ vT, const float* __restrict__ x1,
    float* __restrict__ out) {
  __shared__ ushort Ks[2 * 64 * 64];   // [buf][key][d]   swizzled
  __shared__ ushort Vs[2 * 64 * 64];   // [buf][d][key]   swizzled
  __shared__ ushort Ps[256 * 64];      // [qrow][key]     swizzled
  int bid = blockIdx.x;
  int xcd = bid & 7;
  int j   = bid >> 3;               // 0..63
  int qt  = j & 3;
  int pair = xcd * 16 + (j >> 2);   // 0..127 = b*8+h
  int b = pair >> 3;
  int h = pair & 7;
  int t0 = qt * 256;
  int tid  = threadIdx.x;
  int wave = tid >> 6;              // 0..7
  int lane = tid & 63;
  int quad = lane >> 4;
  int l15  = lane & 15;

  // staging: wave w covers rows w*8..w*8+7 (64B lanes -> 8 rows x 8 chunks);
  // source chunk pre-swizzled so LDS[row][p] = global[row][p ^ (row&7)]
  int row8 = lane >> 3;                  // 0..7
  int csw  = ((lane & 7) ^ row8) * 8;    // swizzled source chunk (ushort off)
  const ushort* kst = k + ((size_t)(b * T_ + wave * 8 + row8)) * D_ + h * HD_ + csw;
  const ushort* vst = vT + ((size_t)((b * 8 + h) * 64 + wave * 8 + row8)) * 1024 + csw;
  ushort* KsW = Ks + wave * 512;
  ushort* VsW = Vs + wave * 512;

  auto STAGE = [&](int kt, int buf) {
    __builtin_amdgcn_global_load_lds((const AS1 void*)(kst + (size_t)kt * 64 * D_),
                                     (AS3 void*)(KsW + buf * 4096), 16, 0, 0);
    __builtin_amdgcn_global_load_lds((const AS1 void*)(vst + kt * 64),
                                     (AS3 void*)(VsW + buf * 4096), 16, 0, 0);
  };

  STAGE(0, 0);

  const ushort* qp0 = q + ((size_t)(b * T_ + t0 + wave * 16 + l15)) * D_ + h * HD_;
  const ushort* qp1 = qp0 + (size_t)128 * D_;
  bf16x8 aq0 = *(const bf16x8*)(qp0 + quad * 8);
  bf16x8 aq1 = *(const bf16x8*)(qp0 + 32 + quad * 8);
  bf16x8 aq2 = *(const bf16x8*)(qp1 + quad * 8);
  bf16x8 aq3 = *(const bf16x8*)(qp1 + 32 + quad * 8);

  // read-side swizzled chunk offsets (all reads: row&7 == l15&7)
  int rsw0 = ((quad)     ^ (l15 & 7)) << 3;
  int rsw1 = ((quad + 4) ^ (l15 & 7)) << 3;

  float l_part[2][4] = {{0.f, 0.f, 0.f, 0.f}, {0.f, 0.f, 0.f, 0.f}};
  f32x4 o0[4], o1[4];
  #pragma unroll
  for (int dt = 0; dt < 4; dt++) {
    o0[dt] = (f32x4){0.f, 0.f, 0.f, 0.f};
    o1[dt] = (f32x4){0.f, 0.f, 0.f, 0.f};
  }

  asm volatile("s_waitcnt vmcnt(0)" ::: "memory");
  __syncthreads();

  for (int kt = 0; kt < 16; kt++) {
    int buf = kt & 1;
    if (kt + 1 < 16) STAGE(kt + 1, buf ^ 1);   // DMA into other buffer, in flight under compute
    const ushort* Kb = Ks + buf * 4096;
    const ushort* Vb = Vs + buf * 4096;

    #pragma unroll
    for (int nt = 0; nt < 4; nt++) {
      const ushort* krow = Kb + (nt * 16 + l15) * 64;
      bf16x8 bk0 = *(const bf16x8*)(krow + rsw0);
      bf16x8 bk1 = *(const bf16x8*)(krow + rsw1);
      f32x4 z = (f32x4){0.f, 0.f, 0.f, 0.f};
      f32x4 s0 = MFMA16(aq0, bk0, z, 0, 0, 0);
      s0 = MFMA16(aq1, bk1, s0, 0, 0, 0);
      f32x4 s1 = MFMA16(aq2, bk0, z, 0, 0, 0);
      s1 = MFMA16(aq3, bk1, s1, 0, 0, 0);

      float p0[4], p1[4];
      #pragma unroll
      for (int r = 0; r < 4; r++) {
        p0[r] = __builtin_amdgcn_exp2f(s0[r]);
        p1[r] = __builtin_amdgcn_exp2f(s1[r]);
        l_part[0][r] += p0[r];
        l_part[1][r] += p1[r];
      }
      int cps = nt * 2 + (l15 >> 3);      // unswizzled chunk of this lane's col
      int cbase = l15 & 7;
      #pragma unroll
      for (int hs = 0; hs < 2; hs++) {
        uint32 u01 = cvtpk(hs ? p1[0] : p0[0], hs ? p1[1] : p0[1]);
        uint32 u23 = cvtpk(hs ? p1[2] : p0[2], hs ? p1[3] : p0[3]);
        int rb = hs * 128 + wave * 16 + quad * 4;
        #pragma unroll
        for (int r = 0; r < 4; r++) {
          int off = (rb + r) * 64 + ((cps ^ ((quad * 4 + r) & 7)) << 3) + cbase;
          uint32 uu = (r < 2) ? u01 : u23;
          Ps[off] = (ushort)((r & 1) ? (uu >> 16) : uu);
        }
      }
    }
    // no barrier: each wave reads back only its own Ps rows

    const ushort* prow = Ps + (wave * 16 + l15) * 64;
    bf16x8 ap0 = *(const bf16x8*)(prow + rsw0);
    bf16x8 ap1 = *(const bf16x8*)(prow + rsw1);
    bf16x8 ap2 = *(const bf16x8*)(prow + 8192 + rsw0);
    bf16x8 ap3 = *(const bf16x8*)(prow + 8192 + rsw1);
    #pragma unroll
    for (int dt = 0; dt < 4; dt++) {
      const ushort* vrow = Vb + (dt * 16 + l15) * 64;
      bf16x8 bv0 = *(const bf16x8*)(vrow + rsw0);
      bf16x8 bv1 = *(const bf16x8*)(vrow + rsw1);
      o0[dt] = MFMA16(ap0, bv0, o0[dt], 0, 0, 0);
      o0[dt] = MFMA16(ap1, bv1, o0[dt], 0, 0, 0);
      o1[dt] = MFMA16(ap2, bv0, o1[dt], 0, 0, 0);
      o1[dt] = MFMA16(ap3, bv1, o1[dt], 0, 0, 0);
    }

    __syncthreads();   // publishes next buffer (implicit vmcnt drain) + guards reuse
  }

  #pragma unroll
  for (int s = 0; s < 2; s++) {
    f32x4* oo = s ? o1 : o0;
    #pragma unroll
    for (int r = 0; r < 4; r++) {
      float l = l_part[s][r];
      l += __shfl_xor(l, 1);
      l += __shfl_xor(l, 2);
      l += __shfl_xor(l, 4);
      l += __shfl_xor(l, 8);
      float inv = 1.0f / l;
      int qrow = t0 + s * 128 + wave * 16 + quad * 4 + r;
      size_t base = ((size_t)(b * T_ + qrow)) * D_ + h * HD_;
      #pragma unroll
      for (int dt = 0; dt < 4; dt++) {
        size_t idx = base + dt * 16 + l15;
        out[idx] = x1[idx] + oo[dt][r] * inv;
      }
    }
  }
}

// ---------------- launch ----------------
extern "C" void kernel_launch(void* const* d_in, const int* in_sizes, int n_in,
                              void* d_out, int out_size, void* d_ws, size_t ws_size,
                              hipStream_t stream) {
  (void)in_sizes; (void)n_in; (void)out_size; (void)ws_size;
  const float* x     = (const float*)d_in[0];
  const float* wq    = (const float*)d_in[1];
  const float* wk    = (const float*)d_in[2];
  const float* wv    = (const float*)d_in[3];
  const float* ln1_g = (const float*)d_in[4];
  const float* ln1_b = (const float*)d_in[5];
  const float* se_w1 = (const float*)d_in[6];
  const float* se_w2 = (const float*)d_in[7];
  const float* ffn_g = (const float*)d_in[8];
  const float* ffn_b = (const float*)d_in[9];
  const float* w1    = (const float*)d_in[10];
  const float* b1    = (const float*)d_in[11];
  const float* w2    = (const float*)d_in[12];
  const float* b2    = (const float*)d_in[13];
  float* out = (float*)d_out;
  char* ws = (char*)d_ws;

  // workspace layout (bytes)
  constexpr size_t X1_OFF   = 0;                         // fp32 x1 (32MB)
  constexpr size_t N_OFF    = 33554432;                  // bf16 n / n2 (16MB)
  constexpr size_t Q_OFF    = 50331648;                  // bf16 q (16MB)
  constexpr size_t K_OFF    = 67108864;                  // bf16 k (16MB)
  constexpr size_t V_OFF    = 83886080;                  // bf16 vT (16MB)
  constexpr size_t H_OFF    = 50331648;                  // bf16 h (reuses q/k/vT; 64MB)
  constexpr size_t WQKV_OFF = 117440512;                 // bf16 wqkvT [1536][512]
  constexpr size_t W1T_OFF  = 119013376;                 // bf16 w1T
  constexpr size_t W2T_OFF  = 121110528;                 // bf16 w2T
  constexpr size_t Y_OFF    = 123207680;
  constexpr size_t Z_OFF    = 123273216;
  constexpr size_t GATE_OFF = 123289600;

  float*  x1    = (float*)(ws + X1_OFF);
  ushort* nbuf  = (ushort*)(ws + N_OFF);
  ushort* qb    = (ushort*)(ws + Q_OFF);
  ushort* kb    = (ushort*)(ws + K_OFF);
  ushort* vT    = (ushort*)(ws + V_OFF);
  ushort* hb    = (ushort*)(ws + H_OFF);
  ushort* wqkvT = (ushort*)(ws + WQKV_OFF);
  ushort* w1T   = (ushort*)(ws + W1T_OFF);
  ushort* w2T   = (ushort*)(ws + W2T_OFF);
  float*  yv    = (float*)(ws + Y_OFF);
  float*  zv    = (float*)(ws + Z_OFF);
  float*  gate  = (float*)(ws + GATE_OFF);

  const int M = B_ * T_;  // 16384

  // 1) all weight cast+transposes in one launch
  cast_transpose_all_k<<<2816, 256, 0, stream>>>(wq, wk, wv, w1, w2, wqkvT, w1T, w2T);

  // 2) SE gate (split-K parallel MLPs)
  se_rowmean_k<<<M / 4, 256, 0, stream>>>(x, yv);
  se_mlp1_k<<<dim3(B_, 8), 256, 0, stream>>>(yv, se_w1, zv);
  se_mlp2_k<<<dim3(B_, 8), 256, 0, stream>>>(zv, se_w2, gate);

  // 3) x1 = x*(1+gate); n = LN1(x1) -> bf16
  gate_ln1_k<<<M / 4, 256, 0, stream>>>(x, gate, ln1_g, ln1_b, x1, nbuf);

  // 4) fused QKV GEMM (q scaled log2e/8, v transposed) — BN=128: 768 blocks
  gemm256_k<128><<<(M / 256) * (1536 / 128), 512, 0, stream>>>(
      nbuf, wqkvT, M, 1536, D_, nullptr, nullptr, qb, kb, vT, nullptr, 3);

  // 5) attention: out(d_out) = x1 + attn (256 Q-rows per block, 8 waves)
  attn_k<<<B_ * H_ * (T_ / 256), 512, 0, stream>>>(qb, kb, vT, x1, out);

  // 6) LN2 -> bf16
  ln2_k<<<M / 4, 256, 0, stream>>>(out, ffn_g, ffn_b, nbuf);

  // 7) FFN — FFN1 256x256 (512 blocks = 2 rounds), FFN2 256x128 (256 = 1 round)
  gemm256_k<256><<<(M / 256) * (FFN_ / 256), 512, 0, stream>>>(
      nbuf, w1T, M, FFN_, D_, b1, nullptr, hb, nullptr, nullptr, nullptr, 1);
  gemm256_k<128><<<(M / 256) * (D_ / 128), 512, 0, stream>>>(
      hb, w2T, M, D_, FFN_, b2, out, nullptr, nullptr, nullptr, out, 2);
}

// Round 6
// 308.956 us; speedup vs baseline: 1.1158x; 1.0737x over previous
//
#include <hip/hip_runtime.h>

typedef unsigned int uint32;

using bf16x8 = __attribute__((ext_vector_type(8))) short;
using f32x4  = __attribute__((ext_vector_type(4))) float;

#define B_  16
#define T_  1024
#define D_  512
#define H_  8
#define HD_ 64
#define FFN_ 2048
#define SEH_ 256
#define EPS_ 1e-5f

#define AS1 __attribute__((address_space(1)))
#define AS3 __attribute__((address_space(3)))

__device__ __forceinline__ ushort f2bf(float f) {
  uint32 x = __float_as_uint(f);
  return (ushort)((x + 0x7fffu + ((x >> 16) & 1u)) >> 16);
}
__device__ __forceinline__ float bf2f(ushort u) {
  return __uint_as_float(((uint32)u) << 16);
}
// packed bf16 pair: lo = bf16(a), hi = bf16(b)  (RTNE, one VALU op)
__device__ __forceinline__ uint32 cvtpk(float a, float b) {
  uint32 r;
  asm("v_cvt_pk_bf16_f32 %0, %1, %2" : "=v"(r) : "v"(a), "v"(b));
  return r;
}
// tanh-form GELU (max |err| vs exact ~3e-4, far under threshold + bf16 rounding)
__device__ __forceinline__ float gelu_fast(float v) {
  float u = v * (0.7978845608f + 0.0356774081f * v * v);
  float e = __expf(2.0f * u);
  float t = 1.0f - 2.0f * __builtin_amdgcn_rcpf(e + 1.0f);
  return 0.5f * v * (1.0f + t);
}

// ---------------- fused weight prep: fp32 (K,N) -> bf16 (N,K), all 5 weights ----------------
__global__ __launch_bounds__(256) void cast_transpose_all_k(
    const float* __restrict__ wq, const float* __restrict__ wk,
    const float* __restrict__ wv, const float* __restrict__ w1,
    const float* __restrict__ w2, ushort* __restrict__ wqkvT,
    ushort* __restrict__ w1T, ushort* __restrict__ w2T) {
  __shared__ float tile[32][33];
  int bid = blockIdx.x;
  const float* W; ushort* WT; int K, N, bk, bn;
  if (bid < 768) {
    int w = bid >> 8, r = bid & 255;
    W = (w == 0) ? wq : (w == 1) ? wk : wv;
    WT = wqkvT + (size_t)w * 512 * 512;
    K = 512; N = 512; bk = (r >> 4) * 32; bn = (r & 15) * 32;
  } else if (bid < 1792) {
    int r = bid - 768;
    W = w1; WT = w1T; K = 512; N = 2048; bk = (r >> 6) * 32; bn = (r & 63) * 32;
  } else {
    int r = bid - 1792;
    W = w2; WT = w2T; K = 2048; N = 512; bk = (r >> 4) * 32; bn = (r & 15) * 32;
  }
  int lx = threadIdx.x & 31;
  int ly = threadIdx.x >> 5;  // 0..7
  #pragma unroll
  for (int i = ly; i < 32; i += 8)
    tile[i][lx] = W[(size_t)(bk + i) * N + bn + lx];
  __syncthreads();
  #pragma unroll
  for (int i = ly; i < 32; i += 8)
    WT[(size_t)(bn + i) * K + bk + lx] = f2bf(tile[lx][i]);
}

// ---------------- SE: y[b][t] = mean_D x ----------------
__global__ __launch_bounds__(256) void se_rowmean_k(const float* __restrict__ x,
                                                    float* __restrict__ y) {
  int row  = blockIdx.x * 4 + (threadIdx.x >> 6);
  int lane = threadIdx.x & 63;
  const float4* p = (const float4*)(x + (size_t)row * D_);
  float4 a = p[lane * 2];
  float4 b = p[lane * 2 + 1];
  float s = a.x + a.y + a.z + a.w + b.x + b.y + b.z + b.w;
  #pragma unroll
  for (int m = 1; m < 64; m <<= 1) s += __shfl_xor(s, m);
  if (lane == 0) y[row] = s * (1.0f / D_);
}

// ---------------- SE: z = relu(y @ se_w1) ---- grid (B_, 8), split-K ----------------
__global__ __launch_bounds__(256) void se_mlp1_k(const float* __restrict__ y,
                                                 const float* __restrict__ w1,
                                                 float* __restrict__ z) {
  __shared__ float yb[T_];
  __shared__ float part[8][32];
  int b = blockIdx.x, jt = blockIdx.y;
  int tid = threadIdx.x;
  #pragma unroll
  for (int i = 0; i < 4; i++) yb[tid + i * 256] = y[(size_t)b * T_ + tid + i * 256];
  __syncthreads();
  int tj = tid & 31, tk = tid >> 5;           // 8 k-groups x 32 j
  int j = jt * 32 + tj;
  const float* wp = w1 + (size_t)(tk * 128) * SEH_ + j;
  const float* yp = yb + tk * 128;
  float a0 = 0.f, a1 = 0.f, a2 = 0.f, a3 = 0.f;
  #pragma unroll
  for (int t = 0; t < 128; t += 4) {
    a0 += yp[t]     * wp[(t)     * SEH_];
    a1 += yp[t + 1] * wp[(t + 1) * SEH_];
    a2 += yp[t + 2] * wp[(t + 2) * SEH_];
    a3 += yp[t + 3] * wp[(t + 3) * SEH_];
  }
  part[tk][tj] = (a0 + a1) + (a2 + a3);
  __syncthreads();
  if (tid < 32) {
    float s = 0.f;
    #pragma unroll
    for (int k = 0; k < 8; k++) s += part[k][tid];
    z[(size_t)b * SEH_ + jt * 32 + tid] = fmaxf(s, 0.f);
  }
}

// ---------------- SE: gate = sigmoid(z @ se_w2) ---- grid (B_, 8), split-K ----------------
__global__ __launch_bounds__(256) void se_mlp2_k(const float* __restrict__ z,
                                                 const float* __restrict__ w2,
                                                 float* __restrict__ gate) {
  __shared__ float zb[SEH_];
  __shared__ float part[2][128];
  int b = blockIdx.x, bt = blockIdx.y;
  int tid = threadIdx.x;
  zb[tid & 255] = z[(size_t)b * SEH_ + (tid & 255)];
  __syncthreads();
  int tt = tid & 127, tk = tid >> 7;          // 2 k-groups x 128 t
  int t = bt * 128 + tt;
  const float* wp = w2 + (size_t)(tk * 128) * T_ + t;
  const float* zp = zb + tk * 128;
  float a0 = 0.f, a1 = 0.f, a2 = 0.f, a3 = 0.f;
  #pragma unroll
  for (int j = 0; j < 128; j += 4) {
    a0 += zp[j]     * wp[(j)     * T_];
    a1 += zp[j + 1] * wp[(j + 1) * T_];
    a2 += zp[j + 2] * wp[(j + 2) * T_];
    a3 += zp[j + 3] * wp[(j + 3) * T_];
  }
  part[tk][tt] = (a0 + a1) + (a2 + a3);
  __syncthreads();
  if (tid < 128) {
    float s = part[0][tid] + part[1][tid];
    gate[(size_t)b * T_ + bt * 128 + tid] = 1.0f / (1.0f + __expf(-s));
  }
}

// ---------------- x1 = x*(1+gate); n = LN(x1)*g+b -> bf16 ----------------
__global__ __launch_bounds__(256) void gate_ln1_k(
    const float* __restrict__ x, const float* __restrict__ gate,
    const float* __restrict__ g, const float* __restrict__ beta,
    float* __restrict__ x1, ushort* __restrict__ nbuf) {
  int rid  = blockIdx.x * 4 + (threadIdx.x >> 6);
  int lane = threadIdx.x & 63;
  const float4* xr = (const float4*)(x + (size_t)rid * D_);
  float4 a = xr[lane * 2];
  float4 b = xr[lane * 2 + 1];
  float gv = 1.0f + gate[rid];
  a.x *= gv; a.y *= gv; a.z *= gv; a.w *= gv;
  b.x *= gv; b.y *= gv; b.z *= gv; b.w *= gv;
  float4* x1r = (float4*)(x1 + (size_t)rid * D_);
  x1r[lane * 2]     = a;
  x1r[lane * 2 + 1] = b;
  float s  = a.x + a.y + a.z + a.w + b.x + b.y + b.z + b.w;
  float ss = a.x*a.x + a.y*a.y + a.z*a.z + a.w*a.w + b.x*b.x + b.y*b.y + b.z*b.z + b.w*b.w;
  #pragma unroll
  for (int m = 1; m < 64; m <<= 1) { s += __shfl_xor(s, m); ss += __shfl_xor(ss, m); }
  float mu   = s * (1.0f / D_);
  float var  = ss * (1.0f / D_) - mu * mu;
  float rstd = rsqrtf(var + EPS_);
  const float4* gp = (const float4*)g;
  const float4* bp = (const float4*)beta;
  float4 g0 = gp[lane * 2], g1 = gp[lane * 2 + 1];
  float4 b0 = bp[lane * 2], b1 = bp[lane * 2 + 1];
  union { uint4 v; ushort u[8]; } pk;
  pk.u[0] = f2bf((a.x - mu) * rstd * g0.x + b0.x);
  pk.u[1] = f2bf((a.y - mu) * rstd * g0.y + b0.y);
  pk.u[2] = f2bf((a.z - mu) * rstd * g0.z + b0.z);
  pk.u[3] = f2bf((a.w - mu) * rstd * g0.w + b0.w);
  pk.u[4] = f2bf((b.x - mu) * rstd * g1.x + b1.x);
  pk.u[5] = f2bf((b.y - mu) * rstd * g1.y + b1.y);
  pk.u[6] = f2bf((b.z - mu) * rstd * g1.z + b1.z);
  pk.u[7] = f2bf((b.w - mu) * rstd * g1.w + b1.w);
  *(uint4*)(nbuf + (size_t)rid * D_ + lane * 8) = pk.v;
}

// ---------------- n2 = LN(x2)*g+b -> bf16 ----------------
__global__ __launch_bounds__(256) void ln2_k(
    const float* __restrict__ x2, const float* __restrict__ g,
    const float* __restrict__ beta, ushort* __restrict__ nbuf) {
  int rid  = blockIdx.x * 4 + (threadIdx.x >> 6);
  int lane = threadIdx.x & 63;
  const float4* xr = (const float4*)(x2 + (size_t)rid * D_);
  float4 a = xr[lane * 2];
  float4 b = xr[lane * 2 + 1];
  float s  = a.x + a.y + a.z + a.w + b.x + b.y + b.z + b.w;
  float ss = a.x*a.x + a.y*a.y + a.z*a.z + a.w*a.w + b.x*b.x + b.y*b.y + b.z*b.z + b.w*b.w;
  #pragma unroll
  for (int m = 1; m < 64; m <<= 1) { s += __shfl_xor(s, m); ss += __shfl_xor(ss, m); }
  float mu   = s * (1.0f / D_);
  float var  = ss * (1.0f / D_) - mu * mu;
  float rstd = rsqrtf(var + EPS_);
  const float4* gp = (const float4*)g;
  const float4* bp = (const float4*)beta;
  float4 g0 = gp[lane * 2], g1 = gp[lane * 2 + 1];
  float4 b0 = bp[lane * 2], b1 = bp[lane * 2 + 1];
  union { uint4 v; ushort u[8]; } pk;
  pk.u[0] = f2bf((a.x - mu) * rstd * g0.x + b0.x);
  pk.u[1] = f2bf((a.y - mu) * rstd * g0.y + b0.y);
  pk.u[2] = f2bf((a.z - mu) * rstd * g0.z + b0.z);
  pk.u[3] = f2bf((a.w - mu) * rstd * g0.w + b0.w);
  pk.u[4] = f2bf((b.x - mu) * rstd * g1.x + b1.x);
  pk.u[5] = f2bf((b.y - mu) * rstd * g1.y + b1.y);
  pk.u[6] = f2bf((b.z - mu) * rstd * g1.z + b1.z);
  pk.u[7] = f2bf((b.w - mu) * rstd * g1.w + b1.w);
  *(uint4*)(nbuf + (size_t)rid * D_ + lane * 8) = pk.v;
}

// ---------------- 256-wide bf16 NT GEMM: minimal 2-phase loop, dbuf DMA ----------------
// BM=256, BK=64, BN template (256 or 128). 8 waves (2M x 4N), per-wave C = 128 x BN/4.
// Per K-tile: {STAGE(t+1 -> other buf); all ds_reads; all MFMAs; __syncthreads}.
// ONE barrier per tile. No intra-tile barriers: each wave reads only its own
// fragments from an immutable buffer, so reads/MFMAs interleave freely (compiler
// emits fine-grained lgkmcnt). The tile-end __syncthreads' implicit vmcnt-drain
// waits only on DMA issued a full tile (~1400cy) earlier -> ~zero exposed latency.
// LDS chunk-XOR swizzle via pre-swizzled global source (dest linear) + matching
// ds_read offsets -> conflict-free.
// epi 1: +bias, GELU -> bf16 outB (FFN1); epi 2: +bias,+resid -> f32 outF (FFN2)
// epi 3 (BN=128): fused QKV: n<512 -> q*log2e/8; n<1024 -> k; else v transposed.
// All bf16 outputs LDS-staged for full-line coalesced writes.
#define MFMA16 __builtin_amdgcn_mfma_f32_16x16x32_bf16
template <int BN>
__global__ __launch_bounds__(512, 2) void gemm256_k(
    const ushort* __restrict__ A, const ushort* __restrict__ BT,
    int M, int N, int K,
    const float* __restrict__ bias, const float* __restrict__ resid,
    ushort* __restrict__ outB, ushort* __restrict__ outB2,
    ushort* __restrict__ vTout, float* __restrict__ outF, int epi) {
  constexpr int WNS   = BN / 4;    // wave N-span
  constexpr int NT    = BN / 64;   // 16-col frags per wave (4 or 2)
  constexpr int BROWS = BN / 8;    // B rows staged per wave
  constexpr int BJ    = BN / 64;   // B stage instrs per wave
  __shared__ ushort smem[2 * 256 * 64 + 2 * BN * 64];
  ushort* As = smem;
  ushort* Bs = smem + 2 * 256 * 64;

  int tid  = threadIdx.x;
  int wave = tid >> 6;
  int lane = tid & 63;
  int quad = lane >> 4;
  int l15  = lane & 15;
  int wm   = wave >> 2;   // 0..1
  int wn   = wave & 3;    // 0..3
  int lr   = lane >> 3;   // stage: row within 8-row group
  int lcs  = (lane & 7) ^ lr;  // stage: swizzled source chunk

  int nbk = N / BN;
  int bid = blockIdx.x;
  int xcd = bid & 7;
  int sb  = bid >> 3;
  int n0  = (sb % nbk) * BN;
  int m0  = ((sb / nbk) * 8 + xcd) * 256;

  f32x4 acc[8][NT];
  #pragma unroll
  for (int i = 0; i < 8; i++)
    #pragma unroll
    for (int j = 0; j < NT; j++) acc[i][j] = (f32x4){0.f, 0.f, 0.f, 0.f};

  const ushort* Ag = A  + (size_t)(m0 + wave * 32 + lr) * K + lcs * 8;
  const ushort* Bg = BT + (size_t)(n0 + wave * BROWS + lr) * K + lcs * 8;

  auto STAGE = [&](int t, int buf) {
    int ko = t * 64;
    ushort* da = As + buf * (256 * 64) + wave * (32 * 64);
    #pragma unroll
    for (int j = 0; j < 4; j++)
      __builtin_amdgcn_global_load_lds((const AS1 void*)(Ag + ko + (size_t)(j * 8) * K),
                                       (AS3 void*)(da + j * 512), 16, 0, 0);
    ushort* db = Bs + buf * (BN * 64) + wave * (BROWS * 64);
    #pragma unroll
    for (int j = 0; j < BJ; j++)
      __builtin_amdgcn_global_load_lds((const AS1 void*)(Bg + ko + (size_t)(j * 8) * K),
                                       (AS3 void*)(db + j * 512), 16, 0, 0);
  };

  int ntt = K >> 6;
  STAGE(0, 0);
  __syncthreads();   // implicit vmcnt(0) drain publishes tile 0

  const ushort* Arow = As + (wm * 128 + l15) * 64;
  const ushort* Brow = Bs + (wn * WNS + l15) * 64;
  int c0 = ((0 + quad) ^ (l15 & 7)) * 8;  // k-half 0 swizzled chunk (ushort off)
  int c1 = ((4 + quad) ^ (l15 & 7)) * 8;  // k-half 1

  for (int t = 0; t < ntt; ++t) {
    int cur = t & 1;
    if (t + 1 < ntt) STAGE(t + 1, cur ^ 1);   // DMA into OTHER buffer: no hazard
    const ushort* Ab = Arow + cur * (256 * 64);
    const ushort* Bb = Brow + cur * (BN * 64);

    bf16x8 b[NT][2], a[4][2];
    #pragma unroll
    for (int h = 0; h < NT; h++) {
      b[h][0] = *(const bf16x8*)(Bb + h * 1024 + c0);
      b[h][1] = *(const bf16x8*)(Bb + h * 1024 + c1);
    }
    #pragma unroll
    for (int m4 = 0; m4 < 4; m4++) {
      a[m4][0] = *(const bf16x8*)(Ab + m4 * 1024 + c0);
      a[m4][1] = *(const bf16x8*)(Ab + m4 * 1024 + c1);
    }
    #pragma unroll
    for (int m4 = 0; m4 < 4; m4++)
      #pragma unroll
      for (int h = 0; h < NT; h++) {
        acc[m4][h] = MFMA16(a[m4][0], b[h][0], acc[m4][h], 0, 0, 0);
        acc[m4][h] = MFMA16(a[m4][1], b[h][1], acc[m4][h], 0, 0, 0);
      }
    #pragma unroll
    for (int m4 = 0; m4 < 4; m4++) {
      a[m4][0] = *(const bf16x8*)(Ab + (4 + m4) * 1024 + c0);
      a[m4][1] = *(const bf16x8*)(Ab + (4 + m4) * 1024 + c1);
    }
    #pragma unroll
    for (int m4 = 0; m4 < 4; m4++)
      #pragma unroll
      for (int h = 0; h < NT; h++) {
        acc[4 + m4][h] = MFMA16(a[m4][0], b[h][0], acc[4 + m4][h], 0, 0, 0);
        acc[4 + m4][h] = MFMA16(a[m4][1], b[h][1], acc[4 + m4][h], 0, 0, 0);
      }

    __syncthreads();   // drains t+1's DMA (vmcnt 0) + guards reuse of cur next iter
  }

  // ---------------- epilogues ----------------
  int colbase = n0 + wn * WNS;
  if (epi == 2) {
    // f32 stores: 16 lanes x 4B = 64B fully-dirty aligned lines already
    #pragma unroll
    for (int nt = 0; nt < NT; nt++) {
      int n = colbase + nt * 16 + l15;
      float bv = bias[n];
      #pragma unroll
      for (int mt = 0; mt < 8; mt++) {
        int m = m0 + wm * 128 + mt * 16 + quad * 4;
        #pragma unroll
        for (int r = 0; r < 4; r++) {
          size_t idx = (size_t)(m + r) * N + n;
          outF[idx] = acc[mt][nt][r] + bv + resid[idx];
        }
      }
    }
  } else {
    // K-loop LDS dead for ALL waves (loop ends with __syncthreads) -> safe to reuse
    if (epi == 3 && n0 >= 1024) {
      // v: per-wave LDS transpose -> full-line coalesced vT writes.
      constexpr int TST = 136;              // t-stride (ushorts), 16B-aligned rows
      ushort* tb = smem + wave * (32 * TST);
      #pragma unroll
      for (int nt = 0; nt < NT; nt++) {
        int dloc = nt * 16 + l15;           // 0..31
        #pragma unroll
        for (int mt = 0; mt < 8; mt++) {
          ushort4 pk;
          pk.x = f2bf(acc[mt][nt][0]);
          pk.y = f2bf(acc[mt][nt][1]);
          pk.z = f2bf(acc[mt][nt][2]);
          pk.w = f2bf(acc[mt][nt][3]);
          *(ushort4*)(tb + dloc * TST + mt * 16 + quad * 4) = pk;
        }
      }
      // each wave reads back only its own region: per-wave lgkm ordering suffices
      int dbase = (n0 - 1024) + wn * WNS;   // 32-col span
      int bb = m0 >> 10;
      int tg = (m0 & 1023) + wm * 128 + l15 * 8;
      #pragma unroll
      for (int j = 0; j < 8; j++) {
        int dloc = j * 4 + quad;            // 0..31
        int d = dbase + dloc;
        int hh = d >> 6, dd = d & 63;
        uint4 vv = *(const uint4*)(tb + dloc * TST + l15 * 8);
        *(uint4*)(vTout + (((size_t)bb * 8 + hh) * 64 + dd) * 1024 + tg) = vv;
      }
    } else {
      // bf16 row-major outputs (epi 1 FFN1-GELU; epi 3 q/k): stage per-wave
      // 32-row x WNS-col chunks in LDS, read back row-major uint4 runs ->
      // every store covers full 64/128-B aligned runs per row.
      constexpr int RS  = WNS + 8;       // padded LDS row stride (ushorts)
      constexpr int LPR = WNS / 8;       // lanes per row (uint4 = 8 ushorts)
      constexpr int RPS = 64 / LPR;      // rows per store instruction
      ushort* tb = smem + wave * (32 * RS);
      ushort* gout; int ldN; float scl;
      if (epi == 1) { gout = outB; ldN = N; scl = 1.0f; }
      else {
        gout = (n0 < 512) ? outB : outB2; ldN = 512;
        // q scaled by 1/8 * log2(e) so attention can use exp2 directly
        scl = (n0 < 512) ? 0.18033688011112042f : 1.0f;
      }
      int ncol = (epi == 1) ? colbase : ((n0 & 511) + wn * WNS);
      float bv[NT];
      #pragma unroll
      for (int nt = 0; nt < NT; nt++)
        bv[nt] = (epi == 1) ? bias[colbase + nt * 16 + l15] : 0.0f;
      int rrow = lane / LPR;
      int seg  = lane % LPR;
      int mrow0 = m0 + wm * 128;
      #pragma unroll
      for (int mtg = 0; mtg < 4; mtg++) {
        #pragma unroll
        for (int mh = 0; mh < 2; mh++) {
          int mt = mtg * 2 + mh;
          #pragma unroll
          for (int nt = 0; nt < NT; nt++) {
            #pragma unroll
            for (int r = 0; r < 4; r++) {
              float v = (epi == 1) ? gelu_fast(acc[mt][nt][r] + bv[nt])
                                   : acc[mt][nt][r] * scl;
              tb[(mh * 16 + quad * 4 + r) * RS + nt * 16 + l15] = f2bf(v);
            }
          }
        }
        #pragma unroll
        for (int it = 0; it < 32 / RPS; it++) {
          int rl = it * RPS + rrow;
          uint4 v = *(const uint4*)(tb + rl * RS + seg * 8);
          *(uint4*)(gout + (size_t)(mrow0 + mtg * 32 + rl) * ldN + ncol + seg * 8) = v;
        }
      }
    }
  }
}

// ---------------- MFMA flash attention, 256 Q-rows/block, 8 waves, no-max softmax ----------------
// (unchanged from round 5 — see comments there)
__global__ __launch_bounds__(512, 2) void attn_k(
    const ushort* __restrict__ q, const ushort* __restrict__ k,
    const ushort* __restrict__ vT, const float* __restrict__ x1,
    float* __restrict__ out) {
  __shared__ ushort Ks[2 * 64 * 64];   // [buf][key][d]   swizzled
  __shared__ ushort Vs[2 * 64 * 64];   // [buf][d][key]   swizzled
  __shared__ ushort Ps[256 * 64];      // [qrow][key]     swizzled
  int bid = blockIdx.x;
  int xcd = bid & 7;
  int j   = bid >> 3;               // 0..63
  int qt  = j & 3;
  int pair = xcd * 16 + (j >> 2);   // 0..127 = b*8+h
  int b = pair >> 3;
  int h = pair & 7;
  int t0 = qt * 256;
  int tid  = threadIdx.x;
  int wave = tid >> 6;              // 0..7
  int lane = tid & 63;
  int quad = lane >> 4;
  int l15  = lane & 15;

  // staging: wave w covers rows w*8..w*8+7 (64B lanes -> 8 rows x 8 chunks);
  // source chunk pre-swizzled so LDS[row][p] = global[row][p ^ (row&7)]
  int row8 = lane >> 3;                  // 0..7
  int csw  = ((lane & 7) ^ row8) * 8;    // swizzled source chunk (ushort off)
  const ushort* kst = k + ((size_t)(b * T_ + wave * 8 + row8)) * D_ + h * HD_ + csw;
  const ushort* vst = vT + ((size_t)((b * 8 + h) * 64 + wave * 8 + row8)) * 1024 + csw;
  ushort* KsW = Ks + wave * 512;
  ushort* VsW = Vs + wave * 512;

  auto STAGE = [&](int kt, int buf) {
    __builtin_amdgcn_global_load_lds((const AS1 void*)(kst + (size_t)kt * 64 * D_),
                                     (AS3 void*)(KsW + buf * 4096), 16, 0, 0);
    __builtin_amdgcn_global_load_lds((const AS1 void*)(vst + kt * 64),
                                     (AS3 void*)(VsW + buf * 4096), 16, 0, 0);
  };

  STAGE(0, 0);

  const ushort* qp0 = q + ((size_t)(b * T_ + t0 + wave * 16 + l15)) * D_ + h * HD_;
  const ushort* qp1 = qp0 + (size_t)128 * D_;
  bf16x8 aq0 = *(const bf16x8*)(qp0 + quad * 8);
  bf16x8 aq1 = *(const bf16x8*)(qp0 + 32 + quad * 8);
  bf16x8 aq2 = *(const bf16x8*)(qp1 + quad * 8);
  bf16x8 aq3 = *(const bf16x8*)(qp1 + 32 + quad * 8);

  // read-side swizzled chunk offsets (all reads: row&7 == l15&7)
  int rsw0 = ((quad)     ^ (l15 & 7)) << 3;
  int rsw1 = ((quad + 4) ^ (l15 & 7)) << 3;

  float l_part[2][4] = {{0.f, 0.f, 0.f, 0.f}, {0.f, 0.f, 0.f, 0.f}};
  f32x4 o0[4], o1[4];
  #pragma unroll
  for (int dt = 0; dt < 4; dt++) {
    o0[dt] = (f32x4){0.f, 0.f, 0.f, 0.f};
    o1[dt] = (f32x4){0.f, 0.f, 0.f, 0.f};
  }

  asm volatile("s_waitcnt vmcnt(0)" ::: "memory");
  __syncthreads();

  for (int kt = 0; kt < 16; kt++) {
    int buf = kt & 1;
    if (kt + 1 < 16) STAGE(kt + 1, buf ^ 1);   // DMA into other buffer, in flight under compute
    const ushort* Kb = Ks + buf * 4096;
    const ushort* Vb = Vs + buf * 4096;

    #pragma unroll
    for (int nt = 0; nt < 4; nt++) {
      const ushort* krow = Kb + (nt * 16 + l15) * 64;
      bf16x8 bk0 = *(const bf16x8*)(krow + rsw0);
      bf16x8 bk1 = *(const bf16x8*)(krow + rsw1);
      f32x4 z = (f32x4){0.f, 0.f, 0.f, 0.f};
      f32x4 s0 = MFMA16(aq0, bk0, z, 0, 0, 0);
      s0 = MFMA16(aq1, bk1, s0, 0, 0, 0);
      f32x4 s1 = MFMA16(aq2, bk0, z, 0, 0, 0);
      s1 = MFMA16(aq3, bk1, s1, 0, 0, 0);

      float p0[4], p1[4];
      #pragma unroll
      for (int r = 0; r < 4; r++) {
        p0[r] = __builtin_amdgcn_exp2f(s0[r]);
        p1[r] = __builtin_amdgcn_exp2f(s1[r]);
        l_part[0][r] += p0[r];
        l_part[1][r] += p1[r];
      }
      int cps = nt * 2 + (l15 >> 3);      // unswizzled chunk of this lane's col
      int cbase = l15 & 7;
      #pragma unroll
      for (int hs = 0; hs < 2; hs++) {
        uint32 u01 = cvtpk(hs ? p1[0] : p0[0], hs ? p1[1] : p0[1]);
        uint32 u23 = cvtpk(hs ? p1[2] : p0[2], hs ? p1[3] : p0[3]);
        int rb = hs * 128 + wave * 16 + quad * 4;
        #pragma unroll
        for (int r = 0; r < 4; r++) {
          int off = (rb + r) * 64 + ((cps ^ ((quad * 4 + r) & 7)) << 3) + cbase;
          uint32 uu = (r < 2) ? u01 : u23;
          Ps[off] = (ushort)((r & 1) ? (uu >> 16) : uu);
        }
      }
    }
    // no barrier: each wave reads back only its own Ps rows

    const ushort* prow = Ps + (wave * 16 + l15) * 64;
    bf16x8 ap0 = *(const bf16x8*)(prow + rsw0);
    bf16x8 ap1 = *(const bf16x8*)(prow + rsw1);
    bf16x8 ap2 = *(const bf16x8*)(prow + 8192 + rsw0);
    bf16x8 ap3 = *(const bf16x8*)(prow + 8192 + rsw1);
    #pragma unroll
    for (int dt = 0; dt < 4; dt++) {
      const ushort* vrow = Vb + (dt * 16 + l15) * 64;
      bf16x8 bv0 = *(const bf16x8*)(vrow + rsw0);
      bf16x8 bv1 = *(const bf16x8*)(vrow + rsw1);
      o0[dt] = MFMA16(ap0, bv0, o0[dt], 0, 0, 0);
      o0[dt] = MFMA16(ap1, bv1, o0[dt], 0, 0, 0);
      o1[dt] = MFMA16(ap2, bv0, o1[dt], 0, 0, 0);
      o1[dt] = MFMA16(ap3, bv1, o1[dt], 0, 0, 0);
    }

    __syncthreads();   // publishes next buffer (implicit vmcnt drain) + guards reuse
  }

  #pragma unroll
  for (int s = 0; s < 2; s++) {
    f32x4* oo = s ? o1 : o0;
    #pragma unroll
    for (int r = 0; r < 4; r++) {
      float l = l_part[s][r];
      l += __shfl_xor(l, 1);
      l += __shfl_xor(l, 2);
      l += __shfl_xor(l, 4);
      l += __shfl_xor(l, 8);
      float inv = 1.0f / l;
      int qrow = t0 + s * 128 + wave * 16 + quad * 4 + r;
      size_t base = ((size_t)(b * T_ + qrow)) * D_ + h * HD_;
      #pragma unroll
      for (int dt = 0; dt < 4; dt++) {
        size_t idx = base + dt * 16 + l15;
        out[idx] = x1[idx] + oo[dt][r] * inv;
      }
    }
  }
}

// ---------------- launch ----------------
extern "C" void kernel_launch(void* const* d_in, const int* in_sizes, int n_in,
                              void* d_out, int out_size, void* d_ws, size_t ws_size,
                              hipStream_t stream) {
  (void)in_sizes; (void)n_in; (void)out_size; (void)ws_size;
  const float* x     = (const float*)d_in[0];
  const float* wq    = (const float*)d_in[1];
  const float* wk    = (const float*)d_in[2];
  const float* wv    = (const float*)d_in[3];
  const float* ln1_g = (const float*)d_in[4];
  const float* ln1_b = (const float*)d_in[5];
  const float* se_w1 = (const float*)d_in[6];
  const float* se_w2 = (const float*)d_in[7];
  const float* ffn_g = (const float*)d_in[8];
  const float* ffn_b = (const float*)d_in[9];
  const float* w1    = (const float*)d_in[10];
  const float* b1    = (const float*)d_in[11];
  const float* w2    = (const float*)d_in[12];
  const float* b2    = (const float*)d_in[13];
  float* out = (float*)d_out;
  char* ws = (char*)d_ws;

  // workspace layout (bytes)
  constexpr size_t X1_OFF   = 0;                         // fp32 x1 (32MB)
  constexpr size_t N_OFF    = 33554432;                  // bf16 n / n2 (16MB)
  constexpr size_t Q_OFF    = 50331648;                  // bf16 q (16MB)
  constexpr size_t K_OFF    = 67108864;                  // bf16 k (16MB)
  constexpr size_t V_OFF    = 83886080;                  // bf16 vT (16MB)
  constexpr size_t H_OFF    = 50331648;                  // bf16 h (reuses q/k/vT; 64MB)
  constexpr size_t WQKV_OFF = 117440512;                 // bf16 wqkvT [1536][512]
  constexpr size_t W1T_OFF  = 119013376;                 // bf16 w1T
  constexpr size_t W2T_OFF  = 121110528;                 // bf16 w2T
  constexpr size_t Y_OFF    = 123207680;
  constexpr size_t Z_OFF    = 123273216;
  constexpr size_t GATE_OFF = 123289600;

  float*  x1    = (float*)(ws + X1_OFF);
  ushort* nbuf  = (ushort*)(ws + N_OFF);
  ushort* qb    = (ushort*)(ws + Q_OFF);
  ushort* kb    = (ushort*)(ws + K_OFF);
  ushort* vT    = (ushort*)(ws + V_OFF);
  ushort* hb    = (ushort*)(ws + H_OFF);
  ushort* wqkvT = (ushort*)(ws + WQKV_OFF);
  ushort* w1T   = (ushort*)(ws + W1T_OFF);
  ushort* w2T   = (ushort*)(ws + W2T_OFF);
  float*  yv    = (float*)(ws + Y_OFF);
  float*  zv    = (float*)(ws + Z_OFF);
  float*  gate  = (float*)(ws + GATE_OFF);

  const int M = B_ * T_;  // 16384

  // 1) all weight cast+transposes in one launch
  cast_transpose_all_k<<<2816, 256, 0, stream>>>(wq, wk, wv, w1, w2, wqkvT, w1T, w2T);

  // 2) SE gate (split-K parallel MLPs)
  se_rowmean_k<<<M / 4, 256, 0, stream>>>(x, yv);
  se_mlp1_k<<<dim3(B_, 8), 256, 0, stream>>>(yv, se_w1, zv);
  se_mlp2_k<<<dim3(B_, 8), 256, 0, stream>>>(zv, se_w2, gate);

  // 3) x1 = x*(1+gate); n = LN1(x1) -> bf16
  gate_ln1_k<<<M / 4, 256, 0, stream>>>(x, gate, ln1_g, ln1_b, x1, nbuf);

  // 4) fused QKV GEMM (q scaled log2e/8, v transposed) — BN=128: 768 blocks
  gemm256_k<128><<<(M / 256) * (1536 / 128), 512, 0, stream>>>(
      nbuf, wqkvT, M, 1536, D_, nullptr, nullptr, qb, kb, vT, nullptr, 3);

  // 5) attention: out(d_out) = x1 + attn (256 Q-rows per block, 8 waves)
  attn_k<<<B_ * H_ * (T_ / 256), 512, 0, stream>>>(qb, kb, vT, x1, out);

  // 6) LN2 -> bf16
  ln2_k<<<M / 4, 256, 0, stream>>>(out, ffn_g, ffn_b, nbuf);

  // 7) FFN — FFN1 256x256 (512 blocks = 2 rounds), FFN2 256x128 (256 = 1 round)
  gemm256_k<256><<<(M / 256) * (FFN_ / 256), 512, 0, stream>>>(
      nbuf, w1T, M, FFN_, D_, b1, nullptr, hb, nullptr, nullptr, nullptr, 1);
  gemm256_k<128><<<(M / 256) * (D_ / 128), 512, 0, stream>>>(
      hb, w2T, M, D_, FFN_, b2, out, nullptr, nullptr, nullptr, out, 2);
}